// Round 3
// baseline (951.293 us; speedup 1.0000x reference)
//
#include <hip/hip_runtime.h>
#include <hip/hip_bf16.h>

// Problem constants
#define B_    8
#define C_    96
#define N_    3136      // 56*56
#define COUT_ 192
#define NTOK_ 25088     // B_*N_
#define BN_EPS 1e-5f

#define QPAD 100        // Q/K LDS row stride (floats), %4==0 for float4
#define PPAD 68         // P LDS row stride
#define CPAD 68         // cat LDS token stride

typedef __hip_bfloat16 bf16;

// ---------------------------------------------------------------------------
// K1: x [B][C][N] fp32  ->  qT [B][N][C] fp32   (token-major)
__global__ __launch_bounds__(256) void transpose_x(const float* __restrict__ x,
                                                   float* __restrict__ qT) {
    __shared__ float tile[32][33];
    const int nb = blockIdx.x * 32;
    const int cb = blockIdx.y * 32;
    const int b  = blockIdx.z;
    const int tx = threadIdx.x & 31;
    const int ty = threadIdx.x >> 5;    // 0..7
#pragma unroll
    for (int r = 0; r < 32; r += 8)
        tile[ty + r][tx] = x[((size_t)b * C_ + cb + ty + r) * N_ + nb + tx];
    __syncthreads();
#pragma unroll
    for (int r = 0; r < 32; r += 8)
        qT[((size_t)b * N_ + nb + ty + r) * C_ + cb + tx] = tile[tx][ty + r];
}

// K1b: conv_w [O][C2] fp32 -> WT [C2][O] fp32
__global__ __launch_bounds__(256) void transpose_w(const float* __restrict__ w,
                                                   float* __restrict__ WT) {
    __shared__ float tile[32][33];
    const int ob = blockIdx.x * 32;
    const int cb = blockIdx.y * 32;
    const int tx = threadIdx.x & 31;
    const int ty = threadIdx.x >> 5;
#pragma unroll
    for (int r = 0; r < 32; r += 8)
        tile[ty + r][tx] = w[(ob + ty + r) * COUT_ + cb + tx];   // tile[o][c]
    __syncthreads();
#pragma unroll
    for (int r = 0; r < 32; r += 8)
        WT[(cb + ty + r) * COUT_ + ob + tx] = tile[tx][ty + r];  // WT[c][o]
}

// ---------------------------------------------------------------------------
// K2: flash attention, fp32.  attOut[b][n][c] = softmax(q qT) q   (token-major)
// Block: 64 query rows of batch b. 256 threads: tx=tid&15 (j/c tiles), ty=tid>>4 (i tiles).
__global__ __launch_bounds__(256) void flash_attn(const float* __restrict__ qT,
                                                  float* __restrict__ attOut) {
    __shared__ float Qs[64 * QPAD];
    __shared__ float Ks[64 * QPAD];
    __shared__ float Ps[64 * PPAD];

    const int b   = blockIdx.y;
    const int i0  = blockIdx.x * 64;
    const int tid = threadIdx.x;
    const int tx  = tid & 15;
    const int ty  = tid >> 4;
    const int i4  = ty * 4;
    const int c0  = tx * 6;
    const float* qb = qT + (size_t)b * N_ * C_;

    // Load Q tile (rows i0..i0+63)
    for (int e = tid; e < 64 * C_; e += 256) {
        int r = e / C_, c = e - r * C_;
        Qs[r * QPAD + c] = qb[(size_t)(i0 + r) * C_ + c];
    }

    float O[4][6];
    float m_i[4], l_i[4];
#pragma unroll
    for (int ii = 0; ii < 4; ii++) {
        m_i[ii] = -1e30f; l_i[ii] = 0.0f;
#pragma unroll
        for (int cc = 0; cc < 6; cc++) O[ii][cc] = 0.0f;
    }

    for (int mt = 0; mt < N_ / 64; mt++) {
        __syncthreads();   // prev PV reads done (and Q visible on first iter)
        const int m0 = mt * 64;
        for (int e = tid; e < 64 * C_; e += 256) {
            int r = e / C_, c = e - r * C_;
            Ks[r * QPAD + c] = qb[(size_t)(m0 + r) * C_ + c];
        }
        __syncthreads();

        // S = Q K^T : 4x4 register tile per thread
        float acc[4][4];
#pragma unroll
        for (int ii = 0; ii < 4; ii++)
#pragma unroll
            for (int jj = 0; jj < 4; jj++) acc[ii][jj] = 0.0f;

        for (int c4 = 0; c4 < C_; c4 += 4) {
            float4 qv[4], kv[4];
#pragma unroll
            for (int u = 0; u < 4; u++) {
                qv[u] = *(const float4*)&Qs[(i4 + u) * QPAD + c4];
                kv[u] = *(const float4*)&Ks[(tx * 4 + u) * QPAD + c4];
            }
#pragma unroll
            for (int ii = 0; ii < 4; ii++)
#pragma unroll
                for (int jj = 0; jj < 4; jj++) {
                    acc[ii][jj] = fmaf(qv[ii].x, kv[jj].x, acc[ii][jj]);
                    acc[ii][jj] = fmaf(qv[ii].y, kv[jj].y, acc[ii][jj]);
                    acc[ii][jj] = fmaf(qv[ii].z, kv[jj].z, acc[ii][jj]);
                    acc[ii][jj] = fmaf(qv[ii].w, kv[jj].w, acc[ii][jj]);
                }
        }

        // online softmax update (state replicated across the 16 tx lanes)
        float alpha[4];
#pragma unroll
        for (int ii = 0; ii < 4; ii++) {
            float tm = fmaxf(fmaxf(acc[ii][0], acc[ii][1]), fmaxf(acc[ii][2], acc[ii][3]));
#pragma unroll
            for (int d = 1; d < 16; d <<= 1) tm = fmaxf(tm, __shfl_xor(tm, d));
            float mn = fmaxf(m_i[ii], tm);
            alpha[ii] = __expf(m_i[ii] - mn);
            m_i[ii] = mn;
            float4 p;
            p.x = __expf(acc[ii][0] - mn);
            p.y = __expf(acc[ii][1] - mn);
            p.z = __expf(acc[ii][2] - mn);
            p.w = __expf(acc[ii][3] - mn);
            *(float4*)&Ps[(i4 + ii) * PPAD + tx * 4] = p;
            float rs = p.x + p.y + p.z + p.w;
#pragma unroll
            for (int d = 1; d < 16; d <<= 1) rs += __shfl_xor(rs, d);
            l_i[ii] = l_i[ii] * alpha[ii] + rs;
#pragma unroll
            for (int cc = 0; cc < 6; cc++) O[ii][cc] *= alpha[ii];
        }
        __syncthreads();

        // O += P * K
        for (int j = 0; j < 64; j++) {
            float p0 = Ps[(i4 + 0) * PPAD + j];
            float p1 = Ps[(i4 + 1) * PPAD + j];
            float p2 = Ps[(i4 + 2) * PPAD + j];
            float p3 = Ps[(i4 + 3) * PPAD + j];
            float2 k01 = *(const float2*)&Ks[j * QPAD + c0];
            float2 k23 = *(const float2*)&Ks[j * QPAD + c0 + 2];
            float2 k45 = *(const float2*)&Ks[j * QPAD + c0 + 4];
            O[0][0] = fmaf(p0, k01.x, O[0][0]); O[0][1] = fmaf(p0, k01.y, O[0][1]);
            O[0][2] = fmaf(p0, k23.x, O[0][2]); O[0][3] = fmaf(p0, k23.y, O[0][3]);
            O[0][4] = fmaf(p0, k45.x, O[0][4]); O[0][5] = fmaf(p0, k45.y, O[0][5]);
            O[1][0] = fmaf(p1, k01.x, O[1][0]); O[1][1] = fmaf(p1, k01.y, O[1][1]);
            O[1][2] = fmaf(p1, k23.x, O[1][2]); O[1][3] = fmaf(p1, k23.y, O[1][3]);
            O[1][4] = fmaf(p1, k45.x, O[1][4]); O[1][5] = fmaf(p1, k45.y, O[1][5]);
            O[2][0] = fmaf(p2, k01.x, O[2][0]); O[2][1] = fmaf(p2, k01.y, O[2][1]);
            O[2][2] = fmaf(p2, k23.x, O[2][2]); O[2][3] = fmaf(p2, k23.y, O[2][3]);
            O[2][4] = fmaf(p2, k45.x, O[2][4]); O[2][5] = fmaf(p2, k45.y, O[2][5]);
            O[3][0] = fmaf(p3, k01.x, O[3][0]); O[3][1] = fmaf(p3, k01.y, O[3][1]);
            O[3][2] = fmaf(p3, k23.x, O[3][2]); O[3][3] = fmaf(p3, k23.y, O[3][3]);
            O[3][4] = fmaf(p3, k45.x, O[3][4]); O[3][5] = fmaf(p3, k45.y, O[3][5]);
        }
    }

    float* ob = attOut + (size_t)b * N_ * C_;
#pragma unroll
    for (int ii = 0; ii < 4; ii++) {
        float inv = 1.0f / l_i[ii];
        float* row = ob + (size_t)(i0 + i4 + ii) * C_ + c0;
        float2 s01 = make_float2(O[ii][0] * inv, O[ii][1] * inv);
        float2 s23 = make_float2(O[ii][2] * inv, O[ii][3] * inv);
        float2 s45 = make_float2(O[ii][4] * inv, O[ii][5] * inv);
        *(float2*)(row)     = s01;
        *(float2*)(row + 2) = s23;
        *(float2*)(row + 4) = s45;
    }
}

// ---------------------------------------------------------------------------
// K3: 1x1 conv over cat=[x, relu(x-att)] + BN-stat accumulation.
// Block: 64 tokens of batch b. 256 threads: tx=tid&15 (4 tokens), ty=tid>>4 (12 out chans).
__global__ __launch_bounds__(256) void conv_bn_stats(const float* __restrict__ qT,
                                                     const float* __restrict__ attOut,
                                                     const float* __restrict__ WT,
                                                     const float* __restrict__ convb,
                                                     float* __restrict__ y,
                                                     float* __restrict__ sums) {
    __shared__ float cat[2 * C_ * CPAD];   // [c][t], 52.2 KB
    const int b   = blockIdx.x / (N_ / 64);
    const int n0  = (blockIdx.x % (N_ / 64)) * 64;
    const int tid = threadIdx.x;
    const float* qb = qT     + ((size_t)b * N_ + n0) * C_;
    const float* ab = attOut + ((size_t)b * N_ + n0) * C_;

    for (int e = tid; e < 64 * C_; e += 256) {
        int t = e / C_, c = e - t * C_;
        float xv = qb[t * C_ + c];
        float av = ab[t * C_ + c];
        cat[c * CPAD + t]        = xv;
        cat[(C_ + c) * CPAD + t] = fmaxf(xv - av, 0.0f);
    }
    __syncthreads();

    const int tx = tid & 15, ty = tid >> 4;
    const int o0 = ty * 12;
    const int t0 = tx * 4;

    float acc[12][4];
#pragma unroll
    for (int oo = 0; oo < 12; oo++) {
        float bv = convb[o0 + oo];
#pragma unroll
        for (int tt = 0; tt < 4; tt++) acc[oo][tt] = bv;
    }

    for (int c = 0; c < 2 * C_; c++) {
        float4 cv = *(const float4*)&cat[c * CPAD + t0];
        const float4* wrow = (const float4*)&WT[c * COUT_ + o0];
        float4 w0 = wrow[0], w1 = wrow[1], w2 = wrow[2];
        float wv[12] = {w0.x, w0.y, w0.z, w0.w, w1.x, w1.y, w1.z, w1.w,
                        w2.x, w2.y, w2.z, w2.w};
#pragma unroll
        for (int oo = 0; oo < 12; oo++) {
            acc[oo][0] = fmaf(wv[oo], cv.x, acc[oo][0]);
            acc[oo][1] = fmaf(wv[oo], cv.y, acc[oo][1]);
            acc[oo][2] = fmaf(wv[oo], cv.z, acc[oo][2]);
            acc[oo][3] = fmaf(wv[oo], cv.w, acc[oo][3]);
        }
    }

    float* sum  = sums;
    float* ssq  = sums + COUT_;
    float* yb   = y + ((size_t)b * COUT_) * N_ + n0;
#pragma unroll
    for (int oo = 0; oo < 12; oo++) {
        float s = acc[oo][0] + acc[oo][1] + acc[oo][2] + acc[oo][3];
        float q = acc[oo][0] * acc[oo][0] + acc[oo][1] * acc[oo][1]
                + acc[oo][2] * acc[oo][2] + acc[oo][3] * acc[oo][3];
#pragma unroll
        for (int d = 1; d < 16; d <<= 1) {
            s += __shfl_xor(s, d);
            q += __shfl_xor(q, d);
        }
        if (tx == 0) {
            atomicAdd(&sum[o0 + oo], s);
            atomicAdd(&ssq[o0 + oo], q);
        }
        *(float4*)&yb[(size_t)(o0 + oo) * N_ + t0] =
            make_float4(acc[oo][0], acc[oo][1], acc[oo][2], acc[oo][3]);
    }
}

// ---------------------------------------------------------------------------
// K4: finalize BN stats -> per-channel scale/shift
__global__ void finalize_stats(const float* __restrict__ sums,
                               const float* __restrict__ gamma,
                               const float* __restrict__ beta,
                               float* __restrict__ ss) {
    int o = threadIdx.x;
    if (o >= COUT_) return;
    const float invn = 1.0f / (float)NTOK_;
    float mean = sums[o] * invn;
    float var  = sums[COUT_ + o] * invn - mean * mean;
    float sc   = gamma[o] * rsqrtf(var + BN_EPS);
    ss[o]         = sc;
    ss[COUT_ + o] = beta[o] - mean * sc;
}

// K5: y -> BN affine -> exact GELU -> fp32 out
__global__ __launch_bounds__(256) void bn_gelu_out(const float* __restrict__ y,
                                                   const float* __restrict__ ss,
                                                   float* __restrict__ out) {
    const int total4 = (B_ * COUT_ * N_) / 4;
    int i = blockIdx.x * 256 + threadIdx.x;
    if (i >= total4) return;
    int base = i * 4;
    int o = (base / N_) % COUT_;
    float sc = ss[o], sh = ss[COUT_ + o];
    float4 v = *(const float4*)&y[base];
    float u0 = fmaf(v.x, sc, sh), u1 = fmaf(v.y, sc, sh);
    float u2 = fmaf(v.z, sc, sh), u3 = fmaf(v.w, sc, sh);
    const float k = 0.70710678118654752f;
    float4 g;
    g.x = 0.5f * u0 * (1.0f + erff(u0 * k));
    g.y = 0.5f * u1 * (1.0f + erff(u1 * k));
    g.z = 0.5f * u2 * (1.0f + erff(u2 * k));
    g.w = 0.5f * u3 * (1.0f + erff(u3 * k));
    *(float4*)&out[base] = g;
}

// ---------------------------------------------------------------------------
extern "C" void kernel_launch(void* const* d_in, const int* in_sizes, int n_in,
                              void* d_out, int out_size, void* d_ws, size_t ws_size,
                              hipStream_t stream) {
    const float* x     = (const float*)d_in[0];
    const float* w     = (const float*)d_in[1];
    const float* cb    = (const float*)d_in[2];
    const float* gamma = (const float*)d_in[3];
    const float* beta  = (const float*)d_in[4];

    float* ws     = (float*)d_ws;
    float* qT     = ws;                                    // B*N*C
    float* attOut = qT + (size_t)B_ * N_ * C_;             // B*N*C
    float* WT     = attOut + (size_t)B_ * N_ * C_;         // 192*192
    float* y      = WT + COUT_ * COUT_;                    // B*COUT*N
    float* sums   = y + (size_t)B_ * COUT_ * N_;           // 2*COUT
    float* ss     = sums + 2 * COUT_;                      // 2*COUT

    hipMemsetAsync(sums, 0, 2 * COUT_ * sizeof(float), stream);

    transpose_x<<<dim3(N_ / 32, C_ / 32, B_), 256, 0, stream>>>(x, qT);
    transpose_w<<<dim3(COUT_ / 32, COUT_ / 32), 256, 0, stream>>>(w, WT);
    flash_attn<<<dim3(N_ / 64, B_), 256, 0, stream>>>(qT, attOut);
    conv_bn_stats<<<dim3(B_ * (N_ / 64)), 256, 0, stream>>>(qT, attOut, WT, cb, y, sums);
    finalize_stats<<<1, COUT_, 0, stream>>>(sums, gamma, beta, ss);
    bn_gelu_out<<<dim3((B_ * COUT_ * N_ / 4 + 255) / 256), 256, 0, stream>>>(y, ss, (float*)d_out);
}

// Round 4
// 517.971 us; speedup vs baseline: 1.8366x; 1.8366x over previous
//
#include <hip/hip_runtime.h>
#include <hip/hip_bf16.h>

// Problem constants
#define B_    8
#define C_    96
#define N_    3136      // 56*56
#define COUT_ 192
#define NTOK_ 25088     // B_*N_
#define BN_EPS 1e-5f

#define QROW 104        // LDS token-row stride in bf16 (96+8): 52 dw -> 2-way max, 16B-aligned rows
#define VROW 72         // VT / P row stride in bf16 (64+8): 36 dw -> 2-way max, 16B-aligned
#define PROW 72
#define CPAD 68         // cat LDS token stride (fp32)
#define BNC  (B_ * N_ * C_)

typedef __hip_bfloat16 bf16;
typedef unsigned short u16;
typedef __attribute__((ext_vector_type(8))) short short8;   // 8 bf16 = 4 VGPRs (MFMA A/B frag)
typedef __attribute__((ext_vector_type(4))) float f32x4;    // MFMA C/D frag

__device__ __forceinline__ u16 f2bf(float f) {
    union { __hip_bfloat16 h; u16 u; } cv;
    cv.h = __float2bfloat16(f);
    return cv.u;
}
__device__ __forceinline__ float bf2f(u16 v) {
    union { u16 u; __hip_bfloat16 h; } cv;
    cv.u = v;
    return __bfloat162float(cv.h);
}

// ---------------------------------------------------------------------------
// K1: x [B][C][N] fp32 -> xt_hi/xt_lo [B][N][C] bf16 (token-major, hi/lo split)
//                         xc_hi [B][C][N] bf16 (channel-major, for PV B-operand)
__global__ __launch_bounds__(256) void transpose_split(const float* __restrict__ x,
                                                       u16* __restrict__ xt_hi,
                                                       u16* __restrict__ xt_lo,
                                                       u16* __restrict__ xc_hi) {
    __shared__ float tile[32][33];
    const int nb = blockIdx.x * 32;
    const int cb = blockIdx.y * 32;
    const int b  = blockIdx.z;
    const int tx = threadIdx.x & 31;
    const int ty = threadIdx.x >> 5;
#pragma unroll
    for (int r = 0; r < 32; r += 8) {
        size_t idx = ((size_t)b * C_ + cb + ty + r) * N_ + nb + tx;
        float v = x[idx];
        tile[ty + r][tx] = v;
        xc_hi[idx] = f2bf(v);
    }
    __syncthreads();
#pragma unroll
    for (int r = 0; r < 32; r += 8) {
        float v = tile[tx][ty + r];
        u16 h = f2bf(v);
        size_t o = ((size_t)b * N_ + nb + ty + r) * C_ + cb + tx;
        xt_hi[o] = h;
        xt_lo[o] = f2bf(v - bf2f(h));
    }
}

// K1b: conv_w [O][C2] fp32 -> WT [C2][O] fp32
__global__ __launch_bounds__(256) void transpose_w(const float* __restrict__ w,
                                                   float* __restrict__ WT) {
    __shared__ float tile[32][33];
    const int ob = blockIdx.x * 32;
    const int cb = blockIdx.y * 32;
    const int tx = threadIdx.x & 31;
    const int ty = threadIdx.x >> 5;
#pragma unroll
    for (int r = 0; r < 32; r += 8)
        tile[ty + r][tx] = w[(ob + ty + r) * COUT_ + cb + tx];
    __syncthreads();
#pragma unroll
    for (int r = 0; r < 32; r += 8)
        WT[(cb + ty + r) * COUT_ + ob + tx] = tile[tx][ty + r];
}

// ---------------------------------------------------------------------------
// K2: MFMA flash attention. attOut[b][n][c] = softmax(q q^T) q, fp32 out.
// 256 threads = 4 waves; wave wid owns query rows i0+wid*16..+15.
// S = Qhi*Khi + Qhi*Klo + Qlo*Khi (split-precision bf16 -> fp32-accurate logits).
// mfma_f32_16x16x32_bf16 layouts (HW-verified m89/m120):
//   A[m=lane&15][k=(lane>>4)*8+j], B[k=(lane>>4)*8+j][n=lane&15],
//   C/D: col=lane&15, row=(lane>>4)*4+reg.
__global__ __launch_bounds__(256) void flash_attn_mfma(const u16* __restrict__ xt_hi,
                                                       const u16* __restrict__ xt_lo,
                                                       const u16* __restrict__ xc_hi,
                                                       float* __restrict__ attOut) {
    __shared__ u16 Kh[64 * QROW];   // doubles as Q-hi staging before the K loop
    __shared__ u16 Kl[64 * QROW];   // doubles as Q-lo staging
    __shared__ u16 VT[96 * VROW];   // V^T tile: [c][j]
    __shared__ u16 Pb[64 * PROW];   // P tile, wave-private 16-row slices

    const int b    = blockIdx.y;
    const int i0   = blockIdx.x * 64;
    const int tid  = threadIdx.x;
    const int lane = tid & 63;
    const int wid  = tid >> 6;      // 0..3
    const int l15  = lane & 15;
    const int quad = lane >> 4;

    const u16* th = xt_hi + (size_t)b * N_ * C_;
    const u16* tl = xt_lo + (size_t)b * N_ * C_;
    const u16* vh = xc_hi + (size_t)b * C_ * N_;

    // ---- stage Q (rows i0..i0+63) into Kh/Kl, preload A-fragments ----
    for (int e = tid; e < 1536; e += 256) {          // 64 rows x 24 ushort4
        int r = e / 24, c = (e % 24) * 4;
        *(ushort4*)&Kh[r * QROW + c] = *(const ushort4*)&th[(size_t)(i0 + r) * C_ + c];
        *(ushort4*)&Kl[r * QROW + c] = *(const ushort4*)&tl[(size_t)(i0 + r) * C_ + c];
    }
    __syncthreads();
    short8 qh[3], ql[3];
#pragma unroll
    for (int ch = 0; ch < 3; ch++) {
        qh[ch] = *(const short8*)&Kh[(wid * 16 + l15) * QROW + ch * 32 + quad * 8];
        ql[ch] = *(const short8*)&Kl[(wid * 16 + l15) * QROW + ch * 32 + quad * 8];
    }
    __syncthreads();   // all waves done reading Q before K staging overwrites

    f32x4 O[6];
    float m_i[4], l_i[4];
#pragma unroll
    for (int n = 0; n < 6; n++) O[n] = (f32x4){0.f, 0.f, 0.f, 0.f};
#pragma unroll
    for (int r = 0; r < 4; r++) { m_i[r] = -1e30f; l_i[r] = 0.f; }

    for (int kt = 0; kt < N_ / 64; kt++) {
        const int n0 = kt * 64;
        // stage K-tile (64 tokens, hi/lo) and V^T tile (96 c x 64 j)
        for (int e = tid; e < 1536; e += 256) {
            int r = e / 24, c = (e % 24) * 4;
            *(ushort4*)&Kh[r * QROW + c] = *(const ushort4*)&th[(size_t)(n0 + r) * C_ + c];
            *(ushort4*)&Kl[r * QROW + c] = *(const ushort4*)&tl[(size_t)(n0 + r) * C_ + c];
        }
        for (int e = tid; e < 1536; e += 256) {      // 96 rows x 16 ushort4
            int r = e / 16, j = (e % 16) * 4;
            *(ushort4*)&VT[r * VROW + j] = *(const ushort4*)&vh[(size_t)r * N_ + n0 + j];
        }
        __syncthreads();

        // ---- S = Q K^T: 4 j-subtiles x 3 k-chunks x 3 split-terms ----
        f32x4 S[4];
#pragma unroll
        for (int jt = 0; jt < 4; jt++) {
            f32x4 acc = (f32x4){0.f, 0.f, 0.f, 0.f};
#pragma unroll
            for (int ch = 0; ch < 3; ch++) {
                short8 kh = *(const short8*)&Kh[(jt * 16 + l15) * QROW + ch * 32 + quad * 8];
                short8 kl = *(const short8*)&Kl[(jt * 16 + l15) * QROW + ch * 32 + quad * 8];
                acc = __builtin_amdgcn_mfma_f32_16x16x32_bf16(qh[ch], kl, acc, 0, 0, 0);
                acc = __builtin_amdgcn_mfma_f32_16x16x32_bf16(ql[ch], kh, acc, 0, 0, 0);
                acc = __builtin_amdgcn_mfma_f32_16x16x32_bf16(qh[ch], kh, acc, 0, 0, 0);
            }
            S[jt] = acc;
        }

        // ---- online softmax; state replicated across each 16-lane group ----
#pragma unroll
        for (int r = 0; r < 4; r++) {
            float mt = fmaxf(fmaxf(S[0][r], S[1][r]), fmaxf(S[2][r], S[3][r]));
#pragma unroll
            for (int d = 1; d < 16; d <<= 1) mt = fmaxf(mt, __shfl_xor(mt, d));
            float mn = fmaxf(m_i[r], mt);
            float al = __expf(m_i[r] - mn);
            m_i[r] = mn;
            float p0 = __expf(S[0][r] - mn);
            float p1 = __expf(S[1][r] - mn);
            float p2 = __expf(S[2][r] - mn);
            float p3 = __expf(S[3][r] - mn);
            S[0][r] = p0; S[1][r] = p1; S[2][r] = p2; S[3][r] = p3;
            float rs = p0 + p1 + p2 + p3;
#pragma unroll
            for (int d = 1; d < 16; d <<= 1) rs += __shfl_xor(rs, d);
            l_i[r] = l_i[r] * al + rs;
#pragma unroll
            for (int n = 0; n < 6; n++) O[n][r] *= al;
            // write P row (C-layout -> LDS row-major), wave-private rows
            const int prow = (wid * 16 + quad * 4 + r) * PROW;
#pragma unroll
            for (int jt = 0; jt < 4; jt++)
                Pb[prow + jt * 16 + l15] = f2bf(S[jt][r]);
        }

        // ---- O += P V  (A = P in A-layout, B = V^T fragments) ----
        short8 pa0 = *(const short8*)&Pb[(wid * 16 + l15) * PROW + quad * 8];
        short8 pa1 = *(const short8*)&Pb[(wid * 16 + l15) * PROW + 32 + quad * 8];
#pragma unroll
        for (int n = 0; n < 6; n++) {
            short8 v0 = *(const short8*)&VT[(n * 16 + l15) * VROW + quad * 8];
            short8 v1 = *(const short8*)&VT[(n * 16 + l15) * VROW + 32 + quad * 8];
            O[n] = __builtin_amdgcn_mfma_f32_16x16x32_bf16(pa0, v0, O[n], 0, 0, 0);
            O[n] = __builtin_amdgcn_mfma_f32_16x16x32_bf16(pa1, v1, O[n], 0, 0, 0);
        }
        __syncthreads();   // all frag reads done before next tile's staging
    }

    float* ob = attOut + (size_t)b * N_ * C_;
#pragma unroll
    for (int r = 0; r < 4; r++) {
        float inv = 1.0f / l_i[r];
        size_t row = (size_t)(i0 + wid * 16 + quad * 4 + r) * C_;
#pragma unroll
        for (int n = 0; n < 6; n++)
            ob[row + n * 16 + l15] = O[n][r] * inv;
    }
}

// ---------------------------------------------------------------------------
// K3: 1x1 conv over cat=[x, relu(x-att)] + BN-stat accumulation.
// x reconstructed as hi+lo (rel err ~4e-6).
__global__ __launch_bounds__(256) void conv_bn_stats(const u16* __restrict__ xt_hi,
                                                     const u16* __restrict__ xt_lo,
                                                     const float* __restrict__ attOut,
                                                     const float* __restrict__ WT,
                                                     const float* __restrict__ convb,
                                                     float* __restrict__ y,
                                                     float* __restrict__ sums) {
    __shared__ float cat[2 * C_ * CPAD];   // [c][t], 52.2 KB
    const int b   = blockIdx.x / (N_ / 64);
    const int n0  = (blockIdx.x % (N_ / 64)) * 64;
    const int tid = threadIdx.x;
    const u16*   th = xt_hi  + ((size_t)b * N_ + n0) * C_;
    const u16*   tl = xt_lo  + ((size_t)b * N_ + n0) * C_;
    const float* ab = attOut + ((size_t)b * N_ + n0) * C_;

    for (int e = tid; e < 64 * C_; e += 256) {
        int t = e / C_, c = e - t * C_;
        float xv = bf2f(th[t * C_ + c]) + bf2f(tl[t * C_ + c]);
        float av = ab[t * C_ + c];
        cat[c * CPAD + t]        = xv;
        cat[(C_ + c) * CPAD + t] = fmaxf(xv - av, 0.0f);
    }
    __syncthreads();

    const int tx = tid & 15, ty = tid >> 4;
    const int o0 = ty * 12;
    const int t0 = tx * 4;

    float acc[12][4];
#pragma unroll
    for (int oo = 0; oo < 12; oo++) {
        float bv = convb[o0 + oo];
#pragma unroll
        for (int tt = 0; tt < 4; tt++) acc[oo][tt] = bv;
    }

    for (int c = 0; c < 2 * C_; c++) {
        float4 cv = *(const float4*)&cat[c * CPAD + t0];
        const float4* wrow = (const float4*)&WT[c * COUT_ + o0];
        float4 w0 = wrow[0], w1 = wrow[1], w2 = wrow[2];
        float wv[12] = {w0.x, w0.y, w0.z, w0.w, w1.x, w1.y, w1.z, w1.w,
                        w2.x, w2.y, w2.z, w2.w};
#pragma unroll
        for (int oo = 0; oo < 12; oo++) {
            acc[oo][0] = fmaf(wv[oo], cv.x, acc[oo][0]);
            acc[oo][1] = fmaf(wv[oo], cv.y, acc[oo][1]);
            acc[oo][2] = fmaf(wv[oo], cv.z, acc[oo][2]);
            acc[oo][3] = fmaf(wv[oo], cv.w, acc[oo][3]);
        }
    }

    float* sum = sums;
    float* ssq = sums + COUT_;
    float* yb  = y + ((size_t)b * COUT_) * N_ + n0;
#pragma unroll
    for (int oo = 0; oo < 12; oo++) {
        float s = acc[oo][0] + acc[oo][1] + acc[oo][2] + acc[oo][3];
        float q = acc[oo][0] * acc[oo][0] + acc[oo][1] * acc[oo][1]
                + acc[oo][2] * acc[oo][2] + acc[oo][3] * acc[oo][3];
#pragma unroll
        for (int d = 1; d < 16; d <<= 1) {
            s += __shfl_xor(s, d);
            q += __shfl_xor(q, d);
        }
        if (tx == 0) {
            atomicAdd(&sum[o0 + oo], s);
            atomicAdd(&ssq[o0 + oo], q);
        }
        *(float4*)&yb[(size_t)(o0 + oo) * N_ + t0] =
            make_float4(acc[oo][0], acc[oo][1], acc[oo][2], acc[oo][3]);
    }
}

// ---------------------------------------------------------------------------
// K4: finalize BN stats -> per-channel scale/shift
__global__ void finalize_stats(const float* __restrict__ sums,
                               const float* __restrict__ gamma,
                               const float* __restrict__ beta,
                               float* __restrict__ ss) {
    int o = threadIdx.x;
    if (o >= COUT_) return;
    const float invn = 1.0f / (float)NTOK_;
    float mean = sums[o] * invn;
    float var  = sums[COUT_ + o] * invn - mean * mean;
    float sc   = gamma[o] * rsqrtf(var + BN_EPS);
    ss[o]         = sc;
    ss[COUT_ + o] = beta[o] - mean * sc;
}

// K5: y -> BN affine -> exact GELU -> fp32 out
__global__ __launch_bounds__(256) void bn_gelu_out(const float* __restrict__ y,
                                                   const float* __restrict__ ss,
                                                   float* __restrict__ out) {
    const int total4 = (B_ * COUT_ * N_) / 4;
    int i = blockIdx.x * 256 + threadIdx.x;
    if (i >= total4) return;
    int base = i * 4;
    int o = (base / N_) % COUT_;
    float sc = ss[o], sh = ss[COUT_ + o];
    float4 v = *(const float4*)&y[base];
    float u0 = fmaf(v.x, sc, sh), u1 = fmaf(v.y, sc, sh);
    float u2 = fmaf(v.z, sc, sh), u3 = fmaf(v.w, sc, sh);
    const float k = 0.70710678118654752f;
    float4 g;
    g.x = 0.5f * u0 * (1.0f + erff(u0 * k));
    g.y = 0.5f * u1 * (1.0f + erff(u1 * k));
    g.z = 0.5f * u2 * (1.0f + erff(u2 * k));
    g.w = 0.5f * u3 * (1.0f + erff(u3 * k));
    *(float4*)&out[base] = g;
}

// ---------------------------------------------------------------------------
extern "C" void kernel_launch(void* const* d_in, const int* in_sizes, int n_in,
                              void* d_out, int out_size, void* d_ws, size_t ws_size,
                              hipStream_t stream) {
    const float* x     = (const float*)d_in[0];
    const float* w     = (const float*)d_in[1];
    const float* cb    = (const float*)d_in[2];
    const float* gamma = (const float*)d_in[3];
    const float* beta  = (const float*)d_in[4];

    u16* xt_hi = (u16*)d_ws;                         // BNC bf16
    u16* xt_lo = xt_hi + (size_t)BNC;                // BNC bf16
    u16* xc_hi = xt_lo + (size_t)BNC;                // BNC bf16
    float* attOut = (float*)(xc_hi + (size_t)BNC);   // BNC fp32 (offset 16B-aligned)
    float* WT     = attOut + (size_t)BNC;            // 192*192
    float* y      = WT + COUT_ * COUT_;              // B*COUT*N
    float* sums   = y + (size_t)B_ * COUT_ * N_;     // 2*COUT
    float* ss     = sums + 2 * COUT_;                // 2*COUT

    hipMemsetAsync(sums, 0, 2 * COUT_ * sizeof(float), stream);

    transpose_split<<<dim3(N_ / 32, C_ / 32, B_), 256, 0, stream>>>(x, xt_hi, xt_lo, xc_hi);
    transpose_w<<<dim3(COUT_ / 32, COUT_ / 32), 256, 0, stream>>>(w, WT);
    flash_attn_mfma<<<dim3(N_ / 64, B_), 256, 0, stream>>>(xt_hi, xt_lo, xc_hi, attOut);
    conv_bn_stats<<<dim3(B_ * (N_ / 64)), 256, 0, stream>>>(xt_hi, xt_lo, attOut, WT, cb, y, sums);
    finalize_stats<<<1, COUT_, 0, stream>>>(sums, gamma, beta, ss);
    bn_gelu_out<<<dim3((B_ * COUT_ * N_ / 4 + 255) / 256), 256, 0, stream>>>(y, ss, (float*)d_out);
}

// Round 5
// 510.839 us; speedup vs baseline: 1.8622x; 1.0140x over previous
//
#include <hip/hip_runtime.h>
#include <hip/hip_bf16.h>

// Problem constants
#define B_    8
#define C_    96
#define N_    3136      // 56*56
#define COUT_ 192
#define NTOK_ 25088     // B_*N_
#define BN_EPS 1e-5f

#define QROW 104        // LDS token-row stride in bf16 (96+8): 52 dw -> 2-way max, 16B-aligned rows
#define VROW 72         // VT / P row stride in bf16 (64+8): 36 dw -> 2-way max, 16B-aligned
#define PROW 72
#define CPAD 68         // cat LDS token stride (fp32)
#define BNC  (B_ * N_ * C_)
#define KSPLIT_TILE 25  // split0: tiles [0,25), split1: [25,49)

typedef __hip_bfloat16 bf16;
typedef unsigned short u16;
typedef __attribute__((ext_vector_type(8))) short short8;   // 8 bf16 = 4 VGPRs (MFMA A/B frag)
typedef __attribute__((ext_vector_type(4))) float f32x4;    // MFMA C/D frag

__device__ __forceinline__ u16 f2bf(float f) {
    union { __hip_bfloat16 h; u16 u; } cv;
    cv.h = __float2bfloat16(f);
    return cv.u;
}
__device__ __forceinline__ float bf2f(u16 v) {
    union { u16 u; __hip_bfloat16 h; } cv;
    cv.u = v;
    return __bfloat162float(cv.h);
}

// ---------------------------------------------------------------------------
// K1: x [B][C][N] fp32 -> xt_hi/xt_lo [B][N][C] bf16 (token-major, hi/lo split)
//                         xc_hi [B][C][N] bf16 (channel-major, for PV B-operand)
__global__ __launch_bounds__(256) void transpose_split(const float* __restrict__ x,
                                                       u16* __restrict__ xt_hi,
                                                       u16* __restrict__ xt_lo,
                                                       u16* __restrict__ xc_hi) {
    __shared__ float tile[32][33];
    const int nb = blockIdx.x * 32;
    const int cb = blockIdx.y * 32;
    const int b  = blockIdx.z;
    const int tx = threadIdx.x & 31;
    const int ty = threadIdx.x >> 5;
#pragma unroll
    for (int r = 0; r < 32; r += 8) {
        size_t idx = ((size_t)b * C_ + cb + ty + r) * N_ + nb + tx;
        float v = x[idx];
        tile[ty + r][tx] = v;
        xc_hi[idx] = f2bf(v);
    }
    __syncthreads();
#pragma unroll
    for (int r = 0; r < 32; r += 8) {
        float v = tile[tx][ty + r];
        u16 h = f2bf(v);
        size_t o = ((size_t)b * N_ + nb + ty + r) * C_ + cb + tx;
        xt_hi[o] = h;
        xt_lo[o] = f2bf(v - bf2f(h));
    }
}

// K1b: conv_w [O][C2] fp32 -> WT [C2][O] fp32
__global__ __launch_bounds__(256) void transpose_w(const float* __restrict__ w,
                                                   float* __restrict__ WT) {
    __shared__ float tile[32][33];
    const int ob = blockIdx.x * 32;
    const int cb = blockIdx.y * 32;
    const int tx = threadIdx.x & 31;
    const int ty = threadIdx.x >> 5;
#pragma unroll
    for (int r = 0; r < 32; r += 8)
        tile[ty + r][tx] = w[(ob + ty + r) * COUT_ + cb + tx];
    __syncthreads();
#pragma unroll
    for (int r = 0; r < 32; r += 8)
        WT[(cb + ty + r) * COUT_ + ob + tx] = tile[tx][ty + r];
}

// ---------------------------------------------------------------------------
// K2: MFMA flash attention, 2-way split-K (flash-decoding style).
// blockIdx.z = split; split 0 handles K-tiles [0,25), split 1 [25,49).
// Writes UNNORMALIZED partial O plus per-row (m, l) for the merge kernel.
// 256 threads = 4 waves; wave wid owns query rows i0+wid*16..+15.
// S = Qhi*Khi + Qhi*Klo + Qlo*Khi (split-precision bf16 -> fp32-accurate logits).
__global__ __launch_bounds__(256) void flash_attn_mfma(const u16* __restrict__ xt_hi,
                                                       const u16* __restrict__ xt_lo,
                                                       const u16* __restrict__ xc_hi,
                                                       float* __restrict__ Opart,
                                                       float2* __restrict__ ml) {
    __shared__ u16 Kh[64 * QROW];   // doubles as Q-hi staging before the K loop
    __shared__ u16 Kl[64 * QROW];   // doubles as Q-lo staging
    __shared__ u16 VT[96 * VROW];   // V^T tile: [c][j]
    __shared__ u16 Pb[64 * PROW];   // P tile, wave-private 16-row slices

    const int b     = blockIdx.y;
    const int i0    = blockIdx.x * 64;
    const int split = blockIdx.z;
    const int kt0   = split ? KSPLIT_TILE : 0;
    const int kt1   = split ? (N_ / 64) : KSPLIT_TILE;
    const int tid   = threadIdx.x;
    const int lane  = tid & 63;
    const int wid   = tid >> 6;     // 0..3
    const int l15   = lane & 15;
    const int quad  = lane >> 4;

    const u16* th = xt_hi + (size_t)b * N_ * C_;
    const u16* tl = xt_lo + (size_t)b * N_ * C_;
    const u16* vh = xc_hi + (size_t)b * C_ * N_;

    // ---- stage Q (rows i0..i0+63) into Kh/Kl, preload A-fragments ----
    for (int e = tid; e < 1536; e += 256) {          // 64 rows x 24 ushort4
        int r = e / 24, c = (e % 24) * 4;
        *(ushort4*)&Kh[r * QROW + c] = *(const ushort4*)&th[(size_t)(i0 + r) * C_ + c];
        *(ushort4*)&Kl[r * QROW + c] = *(const ushort4*)&tl[(size_t)(i0 + r) * C_ + c];
    }
    __syncthreads();
    short8 qh[3], ql[3];
#pragma unroll
    for (int ch = 0; ch < 3; ch++) {
        qh[ch] = *(const short8*)&Kh[(wid * 16 + l15) * QROW + ch * 32 + quad * 8];
        ql[ch] = *(const short8*)&Kl[(wid * 16 + l15) * QROW + ch * 32 + quad * 8];
    }
    __syncthreads();   // all waves done reading Q before K staging overwrites

    f32x4 O[6];
    float m_i[4], l_i[4];
#pragma unroll
    for (int n = 0; n < 6; n++) O[n] = (f32x4){0.f, 0.f, 0.f, 0.f};
#pragma unroll
    for (int r = 0; r < 4; r++) { m_i[r] = -1e30f; l_i[r] = 0.f; }

    for (int kt = kt0; kt < kt1; kt++) {
        const int n0 = kt * 64;
        // stage K-tile (64 tokens, hi/lo) and V^T tile (96 c x 64 j)
        for (int e = tid; e < 1536; e += 256) {
            int r = e / 24, c = (e % 24) * 4;
            *(ushort4*)&Kh[r * QROW + c] = *(const ushort4*)&th[(size_t)(n0 + r) * C_ + c];
            *(ushort4*)&Kl[r * QROW + c] = *(const ushort4*)&tl[(size_t)(n0 + r) * C_ + c];
        }
        for (int e = tid; e < 1536; e += 256) {      // 96 rows x 16 ushort4
            int r = e / 16, j = (e % 16) * 4;
            *(ushort4*)&VT[r * VROW + j] = *(const ushort4*)&vh[(size_t)r * N_ + n0 + j];
        }
        __syncthreads();

        // ---- S = Q K^T: 4 j-subtiles x 3 k-chunks x 3 split-terms ----
        f32x4 S[4];
#pragma unroll
        for (int jt = 0; jt < 4; jt++) {
            f32x4 acc = (f32x4){0.f, 0.f, 0.f, 0.f};
#pragma unroll
            for (int ch = 0; ch < 3; ch++) {
                short8 kh = *(const short8*)&Kh[(jt * 16 + l15) * QROW + ch * 32 + quad * 8];
                short8 kl = *(const short8*)&Kl[(jt * 16 + l15) * QROW + ch * 32 + quad * 8];
                acc = __builtin_amdgcn_mfma_f32_16x16x32_bf16(qh[ch], kl, acc, 0, 0, 0);
                acc = __builtin_amdgcn_mfma_f32_16x16x32_bf16(ql[ch], kh, acc, 0, 0, 0);
                acc = __builtin_amdgcn_mfma_f32_16x16x32_bf16(qh[ch], kh, acc, 0, 0, 0);
            }
            S[jt] = acc;
        }

        // ---- online softmax; state replicated across each 16-lane group ----
#pragma unroll
        for (int r = 0; r < 4; r++) {
            float mt = fmaxf(fmaxf(S[0][r], S[1][r]), fmaxf(S[2][r], S[3][r]));
#pragma unroll
            for (int d = 1; d < 16; d <<= 1) mt = fmaxf(mt, __shfl_xor(mt, d));
            float mn = fmaxf(m_i[r], mt);
            float al = __expf(m_i[r] - mn);
            m_i[r] = mn;
            float p0 = __expf(S[0][r] - mn);
            float p1 = __expf(S[1][r] - mn);
            float p2 = __expf(S[2][r] - mn);
            float p3 = __expf(S[3][r] - mn);
            float rs = p0 + p1 + p2 + p3;
#pragma unroll
            for (int d = 1; d < 16; d <<= 1) rs += __shfl_xor(rs, d);
            l_i[r] = l_i[r] * al + rs;
#pragma unroll
            for (int n = 0; n < 6; n++) O[n][r] *= al;
            // write P row (C-layout -> LDS row-major), wave-private rows
            const int prow = (wid * 16 + quad * 4 + r) * PROW;
            Pb[prow +      l15] = f2bf(p0);
            Pb[prow + 16 + l15] = f2bf(p1);
            Pb[prow + 32 + l15] = f2bf(p2);
            Pb[prow + 48 + l15] = f2bf(p3);
        }

        // ---- O += P V  (A = P in A-layout, B = V^T fragments) ----
        short8 pa0 = *(const short8*)&Pb[(wid * 16 + l15) * PROW + quad * 8];
        short8 pa1 = *(const short8*)&Pb[(wid * 16 + l15) * PROW + 32 + quad * 8];
#pragma unroll
        for (int n = 0; n < 6; n++) {
            short8 v0 = *(const short8*)&VT[(n * 16 + l15) * VROW + quad * 8];
            short8 v1 = *(const short8*)&VT[(n * 16 + l15) * VROW + 32 + quad * 8];
            O[n] = __builtin_amdgcn_mfma_f32_16x16x32_bf16(pa0, v0, O[n], 0, 0, 0);
            O[n] = __builtin_amdgcn_mfma_f32_16x16x32_bf16(pa1, v1, O[n], 0, 0, 0);
        }
        __syncthreads();   // all frag reads done before next tile's staging
    }

    // ---- epilogue: unnormalized partial O + per-row (m, l) ----
    float* ob = Opart + (size_t)split * BNC + (size_t)b * N_ * C_;
#pragma unroll
    for (int r = 0; r < 4; r++) {
        int row = i0 + wid * 16 + quad * 4 + r;
        size_t rowoff = (size_t)row * C_;
#pragma unroll
        for (int n = 0; n < 6; n++)
            ob[rowoff + n * 16 + l15] = O[n][r];
        if (l15 == 0)
            ml[(size_t)split * NTOK_ + (size_t)b * N_ + row] = make_float2(m_i[r], l_i[r]);
    }
}

// K2b: merge the two split-K partials -> attOut (normalized)
__global__ __launch_bounds__(256) void merge_split(const float* __restrict__ Opart,
                                                   const float2* __restrict__ ml,
                                                   float* __restrict__ attOut) {
    const int total = NTOK_ * 24;          // 24 float4 per row
    int i = blockIdx.x * 256 + threadIdx.x;
    if (i >= total) return;
    int t  = i / 24;
    int c4 = (i - t * 24) * 4;
    float2 ml0 = ml[t];
    float2 ml1 = ml[NTOK_ + t];
    float m  = fmaxf(ml0.x, ml1.x);
    float w0 = __expf(ml0.x - m);
    float w1 = __expf(ml1.x - m);
    float inv = 1.0f / (w0 * ml0.y + w1 * ml1.y);
    size_t off = (size_t)t * C_ + c4;
    float4 a = *(const float4*)&Opart[off];
    float4 bb = *(const float4*)&Opart[(size_t)BNC + off];
    float4 o;
    o.x = (w0 * a.x + w1 * bb.x) * inv;
    o.y = (w0 * a.y + w1 * bb.y) * inv;
    o.z = (w0 * a.z + w1 * bb.z) * inv;
    o.w = (w0 * a.w + w1 * bb.w) * inv;
    *(float4*)&attOut[off] = o;
}

// ---------------------------------------------------------------------------
// K3: 1x1 conv over cat=[x, relu(x-att)] + BN-stat accumulation.
// x reconstructed as hi+lo (rel err ~4e-6).
__global__ __launch_bounds__(256) void conv_bn_stats(const u16* __restrict__ xt_hi,
                                                     const u16* __restrict__ xt_lo,
                                                     const float* __restrict__ attOut,
                                                     const float* __restrict__ WT,
                                                     const float* __restrict__ convb,
                                                     float* __restrict__ y,
                                                     float* __restrict__ sums) {
    __shared__ float cat[2 * C_ * CPAD];   // [c][t], 52.2 KB
    const int b   = blockIdx.x / (N_ / 64);
    const int n0  = (blockIdx.x % (N_ / 64)) * 64;
    const int tid = threadIdx.x;
    const u16*   th = xt_hi  + ((size_t)b * N_ + n0) * C_;
    const u16*   tl = xt_lo  + ((size_t)b * N_ + n0) * C_;
    const float* ab = attOut + ((size_t)b * N_ + n0) * C_;

    for (int e = tid; e < 64 * C_; e += 256) {
        int t = e / C_, c = e - t * C_;
        float xv = bf2f(th[t * C_ + c]) + bf2f(tl[t * C_ + c]);
        float av = ab[t * C_ + c];
        cat[c * CPAD + t]        = xv;
        cat[(C_ + c) * CPAD + t] = fmaxf(xv - av, 0.0f);
    }
    __syncthreads();

    const int tx = tid & 15, ty = tid >> 4;
    const int o0 = ty * 12;
    const int t0 = tx * 4;

    float acc[12][4];
#pragma unroll
    for (int oo = 0; oo < 12; oo++) {
        float bv = convb[o0 + oo];
#pragma unroll
        for (int tt = 0; tt < 4; tt++) acc[oo][tt] = bv;
    }

    for (int c = 0; c < 2 * C_; c++) {
        float4 cv = *(const float4*)&cat[c * CPAD + t0];
        const float4* wrow = (const float4*)&WT[c * COUT_ + o0];
        float4 w0 = wrow[0], w1 = wrow[1], w2 = wrow[2];
        float wv[12] = {w0.x, w0.y, w0.z, w0.w, w1.x, w1.y, w1.z, w1.w,
                        w2.x, w2.y, w2.z, w2.w};
#pragma unroll
        for (int oo = 0; oo < 12; oo++) {
            acc[oo][0] = fmaf(wv[oo], cv.x, acc[oo][0]);
            acc[oo][1] = fmaf(wv[oo], cv.y, acc[oo][1]);
            acc[oo][2] = fmaf(wv[oo], cv.z, acc[oo][2]);
            acc[oo][3] = fmaf(wv[oo], cv.w, acc[oo][3]);
        }
    }

    float* sum = sums;
    float* ssq = sums + COUT_;
    float* yb  = y + ((size_t)b * COUT_) * N_ + n0;
#pragma unroll
    for (int oo = 0; oo < 12; oo++) {
        float s = acc[oo][0] + acc[oo][1] + acc[oo][2] + acc[oo][3];
        float q = acc[oo][0] * acc[oo][0] + acc[oo][1] * acc[oo][1]
                + acc[oo][2] * acc[oo][2] + acc[oo][3] * acc[oo][3];
#pragma unroll
        for (int d = 1; d < 16; d <<= 1) {
            s += __shfl_xor(s, d);
            q += __shfl_xor(q, d);
        }
        if (tx == 0) {
            atomicAdd(&sum[o0 + oo], s);
            atomicAdd(&ssq[o0 + oo], q);
        }
        *(float4*)&yb[(size_t)(o0 + oo) * N_ + t0] =
            make_float4(acc[oo][0], acc[oo][1], acc[oo][2], acc[oo][3]);
    }
}

// ---------------------------------------------------------------------------
// K4: finalize BN stats -> per-channel scale/shift
__global__ void finalize_stats(const float* __restrict__ sums,
                               const float* __restrict__ gamma,
                               const float* __restrict__ beta,
                               float* __restrict__ ss) {
    int o = threadIdx.x;
    if (o >= COUT_) return;
    const float invn = 1.0f / (float)NTOK_;
    float mean = sums[o] * invn;
    float var  = sums[COUT_ + o] * invn - mean * mean;
    float sc   = gamma[o] * rsqrtf(var + BN_EPS);
    ss[o]         = sc;
    ss[COUT_ + o] = beta[o] - mean * sc;
}

// K5: y -> BN affine -> exact GELU -> fp32 out
__global__ __launch_bounds__(256) void bn_gelu_out(const float* __restrict__ y,
                                                   const float* __restrict__ ss,
                                                   float* __restrict__ out) {
    const int total4 = (B_ * COUT_ * N_) / 4;
    int i = blockIdx.x * 256 + threadIdx.x;
    if (i >= total4) return;
    int base = i * 4;
    int o = (base / N_) % COUT_;
    float sc = ss[o], sh = ss[COUT_ + o];
    float4 v = *(const float4*)&y[base];
    float u0 = fmaf(v.x, sc, sh), u1 = fmaf(v.y, sc, sh);
    float u2 = fmaf(v.z, sc, sh), u3 = fmaf(v.w, sc, sh);
    const float k = 0.70710678118654752f;
    float4 g;
    g.x = 0.5f * u0 * (1.0f + erff(u0 * k));
    g.y = 0.5f * u1 * (1.0f + erff(u1 * k));
    g.z = 0.5f * u2 * (1.0f + erff(u2 * k));
    g.w = 0.5f * u3 * (1.0f + erff(u3 * k));
    *(float4*)&out[base] = g;
}

// ---------------------------------------------------------------------------
extern "C" void kernel_launch(void* const* d_in, const int* in_sizes, int n_in,
                              void* d_out, int out_size, void* d_ws, size_t ws_size,
                              hipStream_t stream) {
    const float* x     = (const float*)d_in[0];
    const float* w     = (const float*)d_in[1];
    const float* cb    = (const float*)d_in[2];
    const float* gamma = (const float*)d_in[3];
    const float* beta  = (const float*)d_in[4];

    u16* xt_hi = (u16*)d_ws;                         // BNC bf16
    u16* xt_lo = xt_hi + (size_t)BNC;                // BNC bf16
    u16* xc_hi = xt_lo + (size_t)BNC;                // BNC bf16
    float* attOut = (float*)(xc_hi + (size_t)BNC);   // BNC fp32
    float* WT     = attOut + (size_t)BNC;            // 192*192
    float* y      = WT + COUT_ * COUT_;              // B*COUT*N fp32
    float* sums   = y + (size_t)B_ * COUT_ * N_;     // 2*COUT
    float* ss     = sums + 2 * COUT_;                // 2*COUT
    float2* ml    = (float2*)(ss + 2 * COUT_);       // 2*NTOK float2
    // Split-K partials alias y: flash+merge complete before conv writes y.
    float* Opart  = y;                               // 2*BNC fp32 <= y's 2*BNC

    hipMemsetAsync(sums, 0, 2 * COUT_ * sizeof(float), stream);

    transpose_split<<<dim3(N_ / 32, C_ / 32, B_), 256, 0, stream>>>(x, xt_hi, xt_lo, xc_hi);
    transpose_w<<<dim3(COUT_ / 32, COUT_ / 32), 256, 0, stream>>>(w, WT);
    flash_attn_mfma<<<dim3(N_ / 64, B_, 2), 256, 0, stream>>>(xt_hi, xt_lo, xc_hi, Opart, ml);
    merge_split<<<dim3((NTOK_ * 24 + 255) / 256), 256, 0, stream>>>(Opart, ml, attOut);
    conv_bn_stats<<<dim3(B_ * (N_ / 64)), 256, 0, stream>>>(xt_hi, xt_lo, attOut, WT, cb, y, sums);
    finalize_stats<<<1, COUT_, 0, stream>>>(sums, gamma, beta, ss);
    bn_gelu_out<<<dim3((B_ * COUT_ * N_ / 4 + 255) / 256), 256, 0, stream>>>(y, ss, (float*)d_out);
}

// Round 6
// 419.122 us; speedup vs baseline: 2.2697x; 1.2188x over previous
//
#include <hip/hip_runtime.h>
#include <hip/hip_bf16.h>

// Problem constants
#define B_    8
#define C_    96
#define N_    3136      // 56*56
#define COUT_ 192
#define NTOK_ 25088     // B_*N_
#define BN_EPS 1e-5f

#define QROW 104        // K LDS token-row stride in bf16 (96+8), rows 16B-aligned
#define VROW 72         // VT row stride in bf16 (64+8), 16B-aligned
#define PROW 72         // P row stride in bf16
#define CPAD 68         // cat LDS token stride (fp32)
#define BNC  (B_ * N_ * C_)
#define KSPLIT_TILE 25  // split0: tiles [0,25), split1: [25,49)

typedef __hip_bfloat16 bf16;
typedef unsigned short u16;
typedef __attribute__((ext_vector_type(8))) short short8;    // 8 bf16 = 4 VGPRs (MFMA A/B frag)
typedef __attribute__((ext_vector_type(4))) float f32x4;
typedef __attribute__((ext_vector_type(16))) float f32x16;   // 32x32 MFMA C/D frag

__device__ __forceinline__ u16 f2bf(float f) {
    union { __hip_bfloat16 h; u16 u; } cv;
    cv.h = __float2bfloat16(f);
    return cv.u;
}
__device__ __forceinline__ float bf2f(u16 v) {
    union { u16 u; __hip_bfloat16 h; } cv;
    cv.u = v;
    return __bfloat162float(cv.h);
}

// ---------------------------------------------------------------------------
// K1: x [B][C][N] fp32 -> xt_hi/xt_lo [B][N][C] bf16 (token-major, hi/lo split)
//                         xc_hi [B][C][N] bf16 (channel-major, for PV B-operand)
__global__ __launch_bounds__(256) void transpose_split(const float* __restrict__ x,
                                                       u16* __restrict__ xt_hi,
                                                       u16* __restrict__ xt_lo,
                                                       u16* __restrict__ xc_hi) {
    __shared__ float tile[32][33];
    const int nb = blockIdx.x * 32;
    const int cb = blockIdx.y * 32;
    const int b  = blockIdx.z;
    const int tx = threadIdx.x & 31;
    const int ty = threadIdx.x >> 5;
#pragma unroll
    for (int r = 0; r < 32; r += 8) {
        size_t idx = ((size_t)b * C_ + cb + ty + r) * N_ + nb + tx;
        float v = x[idx];
        tile[ty + r][tx] = v;
        xc_hi[idx] = f2bf(v);
    }
    __syncthreads();
#pragma unroll
    for (int r = 0; r < 32; r += 8) {
        float v = tile[tx][ty + r];
        u16 h = f2bf(v);
        size_t o = ((size_t)b * N_ + nb + ty + r) * C_ + cb + tx;
        xt_hi[o] = h;
        xt_lo[o] = f2bf(v - bf2f(h));
    }
}

// K1b: conv_w [O][C2] fp32 -> WT [C2][O] fp32
__global__ __launch_bounds__(256) void transpose_w(const float* __restrict__ w,
                                                   float* __restrict__ WT) {
    __shared__ float tile[32][33];
    const int ob = blockIdx.x * 32;
    const int cb = blockIdx.y * 32;
    const int tx = threadIdx.x & 31;
    const int ty = threadIdx.x >> 5;
#pragma unroll
    for (int r = 0; r < 32; r += 8)
        tile[ty + r][tx] = w[(ob + ty + r) * COUT_ + cb + tx];
    __syncthreads();
#pragma unroll
    for (int r = 0; r < 32; r += 8)
        WT[(cb + ty + r) * COUT_ + ob + tx] = tile[tx][ty + r];
}

// K1c: per-token squared norm + global max (for fixed-max softmax bound)
__global__ __launch_bounds__(256) void token_norms(const float* __restrict__ x,
                                                   float* __restrict__ norm2,
                                                   int* __restrict__ maxbits) {
    const int idx = blockIdx.x * 256 + threadIdx.x;   // 98*256 == NTOK_ exactly
    const int b = idx / N_;
    const int n = idx - b * N_;
    const float* xb = x + (size_t)b * C_ * N_ + n;
    float s = 0.0f;
#pragma unroll
    for (int c = 0; c < C_; c++) {
        float v = xb[(size_t)c * N_];
        s = fmaf(v, v, s);
    }
    norm2[idx] = s;
    float m = s;
#pragma unroll
    for (int d = 1; d < 64; d <<= 1) m = fmaxf(m, __shfl_xor(m, d));
    __shared__ float wmax[4];
    if ((threadIdx.x & 63) == 0) wmax[threadIdx.x >> 6] = m;
    __syncthreads();
    if (threadIdx.x == 0) {
        float mm = fmaxf(fmaxf(wmax[0], wmax[1]), fmaxf(wmax[2], wmax[3]));
        atomicMax(maxbits, __float_as_int(mm));   // norms >= 0 -> int-compare valid
    }
}

// ---------------------------------------------------------------------------
// K2: MFMA flash attention, 32x32x16 shape, fixed-max softmax, 2-way split-K.
// BM=128: 4 waves, wave w owns Q-rows i0+w*32..+31. BN=64 K-tiles.
// S = Qhi*Khi + Qhi*Klo + Qlo*Khi (split-precision, fp32-accurate logits).
// Fixed per-row max m_i = sqrt(norm2_i * max_norm2) >= row max (Cauchy-Schwarz):
// no per-tile max/sum shuffles, no rescaling; l accumulates lane-locally.
// 32x32x16_bf16 layouts: A[m=lane&31][k=(lane>>5)*8+j], B[k=(lane>>5)*8+j][n=lane&31],
// C/D: col=lane&31, row=(reg&3)+8*(reg>>2)+4*(lane>>5)  [C/D HW-verified m74/m101].
__global__ __launch_bounds__(256) void flash_attn_mfma32(const u16* __restrict__ xt_hi,
                                                         const u16* __restrict__ xt_lo,
                                                         const u16* __restrict__ xc_hi,
                                                         const float* __restrict__ norm2,
                                                         const int* __restrict__ maxbits,
                                                         float* __restrict__ Opart,
                                                         float2* __restrict__ ml) {
    __shared__ u16 Kh[64 * QROW];
    __shared__ u16 Kl[64 * QROW];
    __shared__ u16 VT[96 * VROW];    // [channel][token]
    __shared__ u16 Pb[128 * PROW];   // wave-private 32-row slices

    const int b     = blockIdx.y;
    const int i0    = blockIdx.x * 128;
    const int split = blockIdx.z;
    const int kt0   = split ? KSPLIT_TILE : 0;
    const int kt1   = split ? (N_ / 64) : KSPLIT_TILE;
    const int tid   = threadIdx.x;
    const int lane  = tid & 63;
    const int w     = tid >> 6;      // 0..3
    const int col   = lane & 31;
    const int g     = lane >> 5;     // 0..1

    const u16* th = xt_hi + (size_t)b * N_ * C_;
    const u16* tl = xt_lo + (size_t)b * N_ * C_;
    const u16* vh = xc_hi + (size_t)b * C_ * N_;

    // ---- Q A-fragments straight from global (once per block) ----
    const int qrow  = i0 + w * 32 + col;
    const int qrowc = qrow < N_ ? qrow : N_ - 1;
    short8 qh[6], ql[6];
#pragma unroll
    for (int kc = 0; kc < 6; kc++) {
        qh[kc] = *(const short8*)&th[(size_t)qrowc * C_ + kc * 16 + g * 8];
        ql[kc] = *(const short8*)&tl[(size_t)qrowc * C_ + kc * 16 + g * 8];
    }

    // ---- fixed per-row softmax bound ----
    const float maxn2 = __int_as_float(*maxbits);
    float m_r[16], l_acc[16];
    int rrow[16];
#pragma unroll
    for (int r = 0; r < 16; r++) {
        int row = i0 + w * 32 + (r & 3) + 8 * (r >> 2) + 4 * g;
        rrow[r] = row;
        int rc = row < N_ ? row : N_ - 1;
        m_r[r] = sqrtf(norm2[(size_t)b * N_ + rc] * maxn2);
        l_acc[r] = 0.0f;
    }

    f32x16 O0 = {0}, O1 = {0}, O2 = {0};

    for (int kt = kt0; kt < kt1; kt++) {
        const int n0 = kt * 64;
        __syncthreads();   // prior frag reads done before restaging
        for (int e = tid; e < 1536; e += 256) {       // K: 64 rows x 24 ushort4
            int r = e / 24, c = (e % 24) * 4;
            *(ushort4*)&Kh[r * QROW + c] = *(const ushort4*)&th[(size_t)(n0 + r) * C_ + c];
            *(ushort4*)&Kl[r * QROW + c] = *(const ushort4*)&tl[(size_t)(n0 + r) * C_ + c];
        }
        for (int e = tid; e < 1536; e += 256) {       // V^T: 96 rows x 16 ushort4
            int r = e / 16, j = (e % 16) * 4;
            *(ushort4*)&VT[r * VROW + j] = *(const ushort4*)&vh[(size_t)r * N_ + n0 + j];
        }
        __syncthreads();

        // ---- S = Q K^T, then p = exp(S - m), P -> LDS (wave-private) ----
#pragma unroll
        for (int jt = 0; jt < 2; jt++) {
            f32x16 S = {0};
#pragma unroll
            for (int kc = 0; kc < 6; kc++) {
                short8 kh = *(const short8*)&Kh[(jt * 32 + col) * QROW + kc * 16 + g * 8];
                short8 kl = *(const short8*)&Kl[(jt * 32 + col) * QROW + kc * 16 + g * 8];
                S = __builtin_amdgcn_mfma_f32_32x32x16_bf16(qh[kc], kl, S, 0, 0, 0);
                S = __builtin_amdgcn_mfma_f32_32x32x16_bf16(ql[kc], kh, S, 0, 0, 0);
                S = __builtin_amdgcn_mfma_f32_32x32x16_bf16(qh[kc], kh, S, 0, 0, 0);
            }
#pragma unroll
            for (int r = 0; r < 16; r++) {
                float p = __expf(S[r] - m_r[r]);
                l_acc[r] += p;
                int prow = w * 32 + (r & 3) + 8 * (r >> 2) + 4 * g;
                Pb[prow * PROW + jt * 32 + col] = f2bf(p);
            }
        }

        // ---- O += P V (same-wave LDS round-trip, DS pipe is in-order/wave) ----
        short8 pa[4];
#pragma unroll
        for (int kc = 0; kc < 4; kc++)
            pa[kc] = *(const short8*)&Pb[(w * 32 + col) * PROW + kc * 16 + g * 8];
#pragma unroll
        for (int kc = 0; kc < 4; kc++) {
            short8 v0 = *(const short8*)&VT[(col)      * VROW + kc * 16 + g * 8];
            short8 v1 = *(const short8*)&VT[(32 + col) * VROW + kc * 16 + g * 8];
            short8 v2 = *(const short8*)&VT[(64 + col) * VROW + kc * 16 + g * 8];
            O0 = __builtin_amdgcn_mfma_f32_32x32x16_bf16(pa[kc], v0, O0, 0, 0, 0);
            O1 = __builtin_amdgcn_mfma_f32_32x32x16_bf16(pa[kc], v1, O1, 0, 0, 0);
            O2 = __builtin_amdgcn_mfma_f32_32x32x16_bf16(pa[kc], v2, O2, 0, 0, 0);
        }
    }

    // ---- reduce l across the 32 columns (within each 32-lane half) ----
#pragma unroll
    for (int r = 0; r < 16; r++) {
        float l = l_acc[r];
#pragma unroll
        for (int d = 1; d < 32; d <<= 1) l += __shfl_xor(l, d);
        l_acc[r] = l;
    }

    // ---- epilogue: unnormalized partial O + per-row (m, l) ----
    float* ob = Opart + (size_t)split * BNC + (size_t)b * N_ * C_;
#pragma unroll
    for (int r = 0; r < 16; r++) {
        int row = rrow[r];
        if (row < N_) {
            size_t rowoff = (size_t)row * C_;
            ob[rowoff +      col] = O0[r];
            ob[rowoff + 32 + col] = O1[r];
            ob[rowoff + 64 + col] = O2[r];
            if (col == 0)
                ml[(size_t)split * NTOK_ + (size_t)b * N_ + row] = make_float2(m_r[r], l_acc[r]);
        }
    }
}

// K2b: merge the two split-K partials -> attOut (normalized)
__global__ __launch_bounds__(256) void merge_split(const float* __restrict__ Opart,
                                                   const float2* __restrict__ ml,
                                                   float* __restrict__ attOut) {
    const int total = NTOK_ * 24;          // 24 float4 per row
    int i = blockIdx.x * 256 + threadIdx.x;
    if (i >= total) return;
    int t  = i / 24;
    int c4 = (i - t * 24) * 4;
    float2 ml0 = ml[t];
    float2 ml1 = ml[NTOK_ + t];
    float m  = fmaxf(ml0.x, ml1.x);
    float w0 = __expf(ml0.x - m);
    float w1 = __expf(ml1.x - m);
    float inv = 1.0f / (w0 * ml0.y + w1 * ml1.y);
    size_t off = (size_t)t * C_ + c4;
    float4 a  = *(const float4*)&Opart[off];
    float4 bb = *(const float4*)&Opart[(size_t)BNC + off];
    float4 o;
    o.x = (w0 * a.x + w1 * bb.x) * inv;
    o.y = (w0 * a.y + w1 * bb.y) * inv;
    o.z = (w0 * a.z + w1 * bb.z) * inv;
    o.w = (w0 * a.w + w1 * bb.w) * inv;
    *(float4*)&attOut[off] = o;
}

// ---------------------------------------------------------------------------
// K3: 1x1 conv over cat=[x, relu(x-att)] + BN-stat accumulation.
__global__ __launch_bounds__(256) void conv_bn_stats(const u16* __restrict__ xt_hi,
                                                     const u16* __restrict__ xt_lo,
                                                     const float* __restrict__ attOut,
                                                     const float* __restrict__ WT,
                                                     const float* __restrict__ convb,
                                                     float* __restrict__ y,
                                                     float* __restrict__ sums) {
    __shared__ float cat[2 * C_ * CPAD];   // [c][t], 52.2 KB
    const int b   = blockIdx.x / (N_ / 64);
    const int n0  = (blockIdx.x % (N_ / 64)) * 64;
    const int tid = threadIdx.x;
    const u16*   th = xt_hi  + ((size_t)b * N_ + n0) * C_;
    const u16*   tl = xt_lo  + ((size_t)b * N_ + n0) * C_;
    const float* ab = attOut + ((size_t)b * N_ + n0) * C_;

    for (int e = tid; e < 64 * C_; e += 256) {
        int t = e / C_, c = e - t * C_;
        float xv = bf2f(th[t * C_ + c]) + bf2f(tl[t * C_ + c]);
        float av = ab[t * C_ + c];
        cat[c * CPAD + t]        = xv;
        cat[(C_ + c) * CPAD + t] = fmaxf(xv - av, 0.0f);
    }
    __syncthreads();

    const int tx = tid & 15, ty = tid >> 4;
    const int o0 = ty * 12;
    const int t0 = tx * 4;

    float acc[12][4];
#pragma unroll
    for (int oo = 0; oo < 12; oo++) {
        float bv = convb[o0 + oo];
#pragma unroll
        for (int tt = 0; tt < 4; tt++) acc[oo][tt] = bv;
    }

    for (int c = 0; c < 2 * C_; c++) {
        float4 cv = *(const float4*)&cat[c * CPAD + t0];
        const float4* wrow = (const float4*)&WT[c * COUT_ + o0];
        float4 w0 = wrow[0], w1 = wrow[1], w2 = wrow[2];
        float wv[12] = {w0.x, w0.y, w0.z, w0.w, w1.x, w1.y, w1.z, w1.w,
                        w2.x, w2.y, w2.z, w2.w};
#pragma unroll
        for (int oo = 0; oo < 12; oo++) {
            acc[oo][0] = fmaf(wv[oo], cv.x, acc[oo][0]);
            acc[oo][1] = fmaf(wv[oo], cv.y, acc[oo][1]);
            acc[oo][2] = fmaf(wv[oo], cv.z, acc[oo][2]);
            acc[oo][3] = fmaf(wv[oo], cv.w, acc[oo][3]);
        }
    }

    float* sum = sums;
    float* ssq = sums + COUT_;
    float* yb  = y + ((size_t)b * COUT_) * N_ + n0;
#pragma unroll
    for (int oo = 0; oo < 12; oo++) {
        float s = acc[oo][0] + acc[oo][1] + acc[oo][2] + acc[oo][3];
        float q = acc[oo][0] * acc[oo][0] + acc[oo][1] * acc[oo][1]
                + acc[oo][2] * acc[oo][2] + acc[oo][3] * acc[oo][3];
#pragma unroll
        for (int d = 1; d < 16; d <<= 1) {
            s += __shfl_xor(s, d);
            q += __shfl_xor(q, d);
        }
        if (tx == 0) {
            atomicAdd(&sum[o0 + oo], s);
            atomicAdd(&ssq[o0 + oo], q);
        }
        *(float4*)&yb[(size_t)(o0 + oo) * N_ + t0] =
            make_float4(acc[oo][0], acc[oo][1], acc[oo][2], acc[oo][3]);
    }
}

// ---------------------------------------------------------------------------
// K4: finalize BN stats -> per-channel scale/shift
__global__ void finalize_stats(const float* __restrict__ sums,
                               const float* __restrict__ gamma,
                               const float* __restrict__ beta,
                               float* __restrict__ ss) {
    int o = threadIdx.x;
    if (o >= COUT_) return;
    const float invn = 1.0f / (float)NTOK_;
    float mean = sums[o] * invn;
    float var  = sums[COUT_ + o] * invn - mean * mean;
    float sc   = gamma[o] * rsqrtf(var + BN_EPS);
    ss[o]         = sc;
    ss[COUT_ + o] = beta[o] - mean * sc;
}

// K5: y -> BN affine -> exact GELU -> fp32 out
__global__ __launch_bounds__(256) void bn_gelu_out(const float* __restrict__ y,
                                                   const float* __restrict__ ss,
                                                   float* __restrict__ out) {
    const int total4 = (B_ * COUT_ * N_) / 4;
    int i = blockIdx.x * 256 + threadIdx.x;
    if (i >= total4) return;
    int base = i * 4;
    int o = (base / N_) % COUT_;
    float sc = ss[o], sh = ss[COUT_ + o];
    float4 v = *(const float4*)&y[base];
    float u0 = fmaf(v.x, sc, sh), u1 = fmaf(v.y, sc, sh);
    float u2 = fmaf(v.z, sc, sh), u3 = fmaf(v.w, sc, sh);
    const float k = 0.70710678118654752f;
    float4 g;
    g.x = 0.5f * u0 * (1.0f + erff(u0 * k));
    g.y = 0.5f * u1 * (1.0f + erff(u1 * k));
    g.z = 0.5f * u2 * (1.0f + erff(u2 * k));
    g.w = 0.5f * u3 * (1.0f + erff(u3 * k));
    *(float4*)&out[base] = g;
}

// ---------------------------------------------------------------------------
extern "C" void kernel_launch(void* const* d_in, const int* in_sizes, int n_in,
                              void* d_out, int out_size, void* d_ws, size_t ws_size,
                              hipStream_t stream) {
    const float* x     = (const float*)d_in[0];
    const float* w     = (const float*)d_in[1];
    const float* cb    = (const float*)d_in[2];
    const float* gamma = (const float*)d_in[3];
    const float* beta  = (const float*)d_in[4];

    u16* xt_hi = (u16*)d_ws;                         // BNC bf16
    u16* xt_lo = xt_hi + (size_t)BNC;                // BNC bf16
    u16* xc_hi = xt_lo + (size_t)BNC;                // BNC bf16
    float* attOut = (float*)(xc_hi + (size_t)BNC);   // BNC fp32
    float* WT     = attOut + (size_t)BNC;            // 192*192
    float* y      = WT + COUT_ * COUT_;              // B*COUT*N fp32
    float* sums   = y + (size_t)B_ * COUT_ * N_;     // 2*COUT
    float* ss     = sums + 2 * COUT_;                // 2*COUT
    float2* ml    = (float2*)(ss + 2 * COUT_);       // 2*NTOK float2
    float* norm2  = (float*)(ml + 2 * NTOK_);        // NTOK
    int*   maxb   = (int*)(norm2 + NTOK_);           // 1
    // Split-K partials alias y: flash+merge complete before conv writes y.
    float* Opart  = y;                               // 2*BNC fp32 == y's 2*BNC

    hipMemsetAsync(sums, 0, 2 * COUT_ * sizeof(float), stream);
    hipMemsetAsync(maxb, 0, sizeof(int), stream);

    transpose_split<<<dim3(N_ / 32, C_ / 32, B_), 256, 0, stream>>>(x, xt_hi, xt_lo, xc_hi);
    transpose_w<<<dim3(COUT_ / 32, COUT_ / 32), 256, 0, stream>>>(w, WT);
    token_norms<<<dim3(NTOK_ / 256), 256, 0, stream>>>(x, norm2, maxb);
    flash_attn_mfma32<<<dim3((N_ + 127) / 128, B_, 2), 256, 0, stream>>>(
        xt_hi, xt_lo, xc_hi, norm2, maxb, Opart, ml);
    merge_split<<<dim3((NTOK_ * 24 + 255) / 256), 256, 0, stream>>>(Opart, ml, attOut);
    conv_bn_stats<<<dim3(B_ * (N_ / 64)), 256, 0, stream>>>(xt_hi, xt_lo, attOut, WT, cb, y, sums);
    finalize_stats<<<1, COUT_, 0, stream>>>(sums, gamma, beta, ss);
    bn_gelu_out<<<dim3((B_ * COUT_ * N_ / 4 + 255) / 256), 256, 0, stream>>>(y, ss, (float*)d_out);
}

// Round 7
// 408.601 us; speedup vs baseline: 2.3282x; 1.0257x over previous
//
#include <hip/hip_runtime.h>
#include <hip/hip_bf16.h>

// Problem constants
#define B_    8
#define C_    96
#define N_    3136      // 56*56
#define COUT_ 192
#define NTOK_ 25088     // B_*N_
#define BN_EPS 1e-5f

#define QROW 104        // K LDS token-row stride in bf16 (96+8), 16B-multiple rows
#define VROW 72         // VT row stride in bf16 (64+8), 16B-multiple
#define CPAD 68         // cat LDS token stride (fp32)
#define BNC  (B_ * N_ * C_)
#define NSPLIT 4

typedef __hip_bfloat16 bf16;
typedef unsigned short u16;
typedef unsigned int u32;
typedef __attribute__((ext_vector_type(8))) short short8;    // 8 bf16 (MFMA A/B frag)
typedef __attribute__((ext_vector_type(16))) float f32x16;   // 32x32 MFMA C/D frag

__device__ __forceinline__ u16 f2bf(float f) {
    union { __hip_bfloat16 h; u16 u; } cv;
    cv.h = __float2bfloat16(f);
    return cv.u;
}
__device__ __forceinline__ float bf2f(u16 v) {
    union { u16 u; __hip_bfloat16 h; } cv;
    cv.u = v;
    return __bfloat162float(cv.h);
}
__device__ __forceinline__ u32 packbf2(float lo, float hi) {
    return ((u32)f2bf(hi) << 16) | (u32)f2bf(lo);
}

// ---------------------------------------------------------------------------
// K1: x [B][C][N] fp32 -> xt_hi/xt_lo [B][N][C] bf16 (token-major, hi/lo split)
//                         xc_hi [B][C][N] bf16 (channel-major, for V^T staging)
__global__ __launch_bounds__(256) void transpose_split(const float* __restrict__ x,
                                                       u16* __restrict__ xt_hi,
                                                       u16* __restrict__ xt_lo,
                                                       u16* __restrict__ xc_hi) {
    __shared__ float tile[32][33];
    const int nb = blockIdx.x * 32;
    const int cb = blockIdx.y * 32;
    const int b  = blockIdx.z;
    const int tx = threadIdx.x & 31;
    const int ty = threadIdx.x >> 5;
#pragma unroll
    for (int r = 0; r < 32; r += 8) {
        size_t idx = ((size_t)b * C_ + cb + ty + r) * N_ + nb + tx;
        float v = x[idx];
        tile[ty + r][tx] = v;
        xc_hi[idx] = f2bf(v);
    }
    __syncthreads();
#pragma unroll
    for (int r = 0; r < 32; r += 8) {
        float v = tile[tx][ty + r];
        u16 h = f2bf(v);
        size_t o = ((size_t)b * N_ + nb + ty + r) * C_ + cb + tx;
        xt_hi[o] = h;
        xt_lo[o] = f2bf(v - bf2f(h));
    }
}

// K1b: conv_w [O][C2] fp32 -> WT [C2][O] fp32
__global__ __launch_bounds__(256) void transpose_w(const float* __restrict__ w,
                                                   float* __restrict__ WT) {
    __shared__ float tile[32][33];
    const int ob = blockIdx.x * 32;
    const int cb = blockIdx.y * 32;
    const int tx = threadIdx.x & 31;
    const int ty = threadIdx.x >> 5;
#pragma unroll
    for (int r = 0; r < 32; r += 8)
        tile[ty + r][tx] = w[(ob + ty + r) * COUT_ + cb + tx];
    __syncthreads();
#pragma unroll
    for (int r = 0; r < 32; r += 8)
        WT[(cb + ty + r) * COUT_ + ob + tx] = tile[tx][ty + r];
}

// K1c: per-token squared norm + global max (fixed-max softmax bound)
__global__ __launch_bounds__(256) void token_norms(const float* __restrict__ x,
                                                   float* __restrict__ norm2,
                                                   int* __restrict__ maxbits) {
    const int idx = blockIdx.x * 256 + threadIdx.x;   // 98*256 == NTOK_
    const int b = idx / N_;
    const int n = idx - b * N_;
    const float* xb = x + (size_t)b * C_ * N_ + n;
    float s = 0.0f;
#pragma unroll
    for (int c = 0; c < C_; c++) {
        float v = xb[(size_t)c * N_];
        s = fmaf(v, v, s);
    }
    norm2[idx] = s;
    float m = s;
#pragma unroll
    for (int d = 1; d < 64; d <<= 1) m = fmaxf(m, __shfl_xor(m, d));
    __shared__ float wmax[4];
    if ((threadIdx.x & 63) == 0) wmax[threadIdx.x >> 6] = m;
    __syncthreads();
    if (threadIdx.x == 0) {
        float mm = fmaxf(fmaxf(wmax[0], wmax[1]), fmaxf(wmax[2], wmax[3]));
        atomicMax(maxbits, __float_as_int(mm));   // norms >= 0 -> int compare ok
    }
}

// ---------------------------------------------------------------------------
// K2: MFMA flash attention, transposed-S formulation, 4-way split-K.
// S^T = K Q^T  (A=K-token rows, B=Q rows) -> C/D lane holds ONE q-row (col),
// 16 j-tokens in regs.  m_i, l are scalars per lane.  P^T B-frags for
// O^T = V^T P^T are assembled in-register via lane^32 shuffles (no P LDS).
// O^T C/D layout is channel-major -> coalesced atomicAdd into attT[b][c][n].
// Fixed max is split-independent -> splits just atomic-accumulate O and l.
// Frag maps (HW-confirmed by R6 pass): A[m=lane&31][k=g*8+e],
// B[k=g*8+e][n=lane&31], C/D: col=lane&31, row=(r&3)+8*(r>>2)+4*g.
__global__ __launch_bounds__(256, 3) void flash_attn_mfma32(const u16* __restrict__ xt_hi,
                                                            const u16* __restrict__ xt_lo,
                                                            const u16* __restrict__ xc_hi,
                                                            const float* __restrict__ norm2,
                                                            const int* __restrict__ maxbits,
                                                            float* __restrict__ attT,
                                                            float* __restrict__ l_arr) {
    __shared__ u16 Kh[64 * QROW];    // 13.0 KB
    __shared__ u16 Kl[64 * QROW];    // 13.0 KB
    __shared__ u16 VT[96 * VROW];    // 13.5 KB  -> total 40.4 KB
    const int b     = blockIdx.y;
    const int i0    = blockIdx.x * 128;
    const int split = blockIdx.z;
    const int kt0   = (49 * split) / NSPLIT;
    const int kt1   = (49 * (split + 1)) / NSPLIT;
    const int tid   = threadIdx.x;
    const int lane  = tid & 63;
    const int w     = tid >> 6;      // wave 0..3: q-rows i0+w*32..+31
    const int col   = lane & 31;
    const int g     = lane >> 5;

    const u16* th = xt_hi + (size_t)b * N_ * C_;
    const u16* tl = xt_lo + (size_t)b * N_ * C_;
    const u16* vh = xc_hi + (size_t)b * C_ * N_;

    // Q B-frags from global, once (lane holds its own q-row)
    const int qrow  = i0 + w * 32 + col;
    const int qrowc = qrow < N_ ? qrow : N_ - 1;
    short8 qh[6], ql[6];
#pragma unroll
    for (int kc = 0; kc < 6; kc++) {
        qh[kc] = *(const short8*)&th[(size_t)qrowc * C_ + kc * 16 + g * 8];
        ql[kc] = *(const short8*)&tl[(size_t)qrowc * C_ + kc * 16 + g * 8];
    }
    const float maxn2 = __int_as_float(*maxbits);
    const float m_i   = sqrtf(norm2[(size_t)b * N_ + qrowc] * maxn2);
    float l_acc = 0.0f;
    f32x16 O0 = {0}, O1 = {0}, O2 = {0};

    for (int kt = kt0; kt < kt1; kt++) {
        const int n0 = kt * 64;
        __syncthreads();   // prior tile's frag reads done
        for (int e = tid; e < 1536; e += 256) {       // K: 64 rows x 24 ushort4
            int r = e / 24, c = (e % 24) * 4;
            *(ushort4*)&Kh[r * QROW + c] = *(const ushort4*)&th[(size_t)(n0 + r) * C_ + c];
            *(ushort4*)&Kl[r * QROW + c] = *(const ushort4*)&tl[(size_t)(n0 + r) * C_ + c];
        }
        for (int e = tid; e < 1536; e += 256) {       // V^T: 96 ch x 16 ushort4
            int r = e / 16, j = (e % 16) * 4;
            *(ushort4*)&VT[r * VROW + j] = *(const ushort4*)&vh[(size_t)r * N_ + n0 + j];
        }
        __syncthreads();

        // ---- S^T = K Q^T per 32-token subtile; p = exp(S-m) packed bf16x2 ----
        u32 w8[2][8];
#pragma unroll
        for (int jt = 0; jt < 2; jt++) {
            f32x16 S = {0};
#pragma unroll
            for (int kc = 0; kc < 6; kc++) {
                short8 kh = *(const short8*)&Kh[(jt * 32 + col) * QROW + kc * 16 + g * 8];
                short8 kl = *(const short8*)&Kl[(jt * 32 + col) * QROW + kc * 16 + g * 8];
                S = __builtin_amdgcn_mfma_f32_32x32x16_bf16(kh, ql[kc], S, 0, 0, 0);
                S = __builtin_amdgcn_mfma_f32_32x32x16_bf16(kl, qh[kc], S, 0, 0, 0);
                S = __builtin_amdgcn_mfma_f32_32x32x16_bf16(kh, qh[kc], S, 0, 0, 0);
            }
            float p[16];
#pragma unroll
            for (int r = 0; r < 16; r++) {
                p[r] = __expf(S[r] - m_i);
                l_acc += p[r];
            }
#pragma unroll
            for (int q = 0; q < 8; q++) w8[jt][q] = packbf2(p[2 * q], p[2 * q + 1]);
        }

        // ---- O^T += V^T P^T ; P^T B-frags via lane^32 exchange ----
#pragma unroll
        for (int kc = 0; kc < 4; kc++) {
            const int jt = kc >> 1, qb = (kc & 1) * 4;
            u32 a0 = w8[jt][qb + 0], a1 = w8[jt][qb + 1];
            u32 a2 = w8[jt][qb + 2], a3 = w8[jt][qb + 3];
            u32 s0 = __shfl_xor((int)a0, 32), s1 = __shfl_xor((int)a1, 32);
            u32 s2 = __shfl_xor((int)a2, 32), s3 = __shfl_xor((int)a3, 32);
            union { short8 v; u32 u[4]; } Bf;
            Bf.u[0] = g ? s2 : a0;
            Bf.u[1] = g ? s3 : a1;
            Bf.u[2] = g ? a2 : s0;
            Bf.u[3] = g ? a3 : s1;
            short8 v0 = *(const short8*)&VT[(col)      * VROW + kc * 16 + g * 8];
            short8 v1 = *(const short8*)&VT[(32 + col) * VROW + kc * 16 + g * 8];
            short8 v2 = *(const short8*)&VT[(64 + col) * VROW + kc * 16 + g * 8];
            O0 = __builtin_amdgcn_mfma_f32_32x32x16_bf16(v0, Bf.v, O0, 0, 0, 0);
            O1 = __builtin_amdgcn_mfma_f32_32x32x16_bf16(v1, Bf.v, O1, 0, 0, 0);
            O2 = __builtin_amdgcn_mfma_f32_32x32x16_bf16(v2, Bf.v, O2, 0, 0, 0);
        }
    }

    // ---- accumulate unnormalized partials (fixed m -> splits just add) ----
    if (qrow < N_) {
        float* ab = attT + (size_t)b * C_ * N_ + qrow;
#pragma unroll
        for (int r = 0; r < 16; r++) {
            int c = (r & 3) + 8 * (r >> 2) + 4 * g;
            atomicAdd(&ab[(size_t)(c)      * N_], O0[r]);
            atomicAdd(&ab[(size_t)(c + 32) * N_], O1[r]);
            atomicAdd(&ab[(size_t)(c + 64) * N_], O2[r]);
        }
        float l_tot = l_acc + __shfl_xor(l_acc, 32);
        if (g == 0) atomicAdd(&l_arr[(size_t)b * N_ + qrow], l_tot);
    }
}

// ---------------------------------------------------------------------------
// K3: 1x1 conv over cat=[x, relu(x - att/l)] + BN-stat accumulation.
// x (fp32 exact) and attT both channel-major; att normalized on load.
__global__ __launch_bounds__(256) void conv_bn_stats(const float* __restrict__ x,
                                                     const float* __restrict__ attT,
                                                     const float* __restrict__ l_arr,
                                                     const float* __restrict__ WT,
                                                     const float* __restrict__ convb,
                                                     float* __restrict__ y,
                                                     float* __restrict__ sums) {
    __shared__ float cat[2 * C_ * CPAD];   // [c][t], 52.2 KB
    __shared__ float invl[64];
    const int b   = blockIdx.x / (N_ / 64);
    const int n0  = (blockIdx.x % (N_ / 64)) * 64;
    const int tid = threadIdx.x;

    if (tid < 64) invl[tid] = 1.0f / l_arr[(size_t)b * N_ + n0 + tid];
    __syncthreads();

    const float* xb = x    + (size_t)b * C_ * N_ + n0;
    const float* ab = attT + (size_t)b * C_ * N_ + n0;
    for (int e = tid; e < 64 * C_; e += 256) {
        int c = e >> 6, t = e & 63;
        float xv = xb[(size_t)c * N_ + t];
        float au = ab[(size_t)c * N_ + t];
        cat[c * CPAD + t]        = xv;
        cat[(C_ + c) * CPAD + t] = fmaxf(xv - au * invl[t], 0.0f);
    }
    __syncthreads();

    const int tx = tid & 15, ty = tid >> 4;
    const int o0 = ty * 12;
    const int t0 = tx * 4;

    float acc[12][4];
#pragma unroll
    for (int oo = 0; oo < 12; oo++) {
        float bv = convb[o0 + oo];
#pragma unroll
        for (int tt = 0; tt < 4; tt++) acc[oo][tt] = bv;
    }

    for (int c = 0; c < 2 * C_; c++) {
        float4 cv = *(const float4*)&cat[c * CPAD + t0];
        const float4* wrow = (const float4*)&WT[c * COUT_ + o0];
        float4 w0 = wrow[0], w1 = wrow[1], w2 = wrow[2];
        float wv[12] = {w0.x, w0.y, w0.z, w0.w, w1.x, w1.y, w1.z, w1.w,
                        w2.x, w2.y, w2.z, w2.w};
#pragma unroll
        for (int oo = 0; oo < 12; oo++) {
            acc[oo][0] = fmaf(wv[oo], cv.x, acc[oo][0]);
            acc[oo][1] = fmaf(wv[oo], cv.y, acc[oo][1]);
            acc[oo][2] = fmaf(wv[oo], cv.z, acc[oo][2]);
            acc[oo][3] = fmaf(wv[oo], cv.w, acc[oo][3]);
        }
    }

    float* sum = sums;
    float* ssq = sums + COUT_;
    float* yb  = y + ((size_t)b * COUT_) * N_ + n0;
#pragma unroll
    for (int oo = 0; oo < 12; oo++) {
        float s = acc[oo][0] + acc[oo][1] + acc[oo][2] + acc[oo][3];
        float q = acc[oo][0] * acc[oo][0] + acc[oo][1] * acc[oo][1]
                + acc[oo][2] * acc[oo][2] + acc[oo][3] * acc[oo][3];
#pragma unroll
        for (int d = 1; d < 16; d <<= 1) {
            s += __shfl_xor(s, d);
            q += __shfl_xor(q, d);
        }
        if (tx == 0) {
            atomicAdd(&sum[o0 + oo], s);
            atomicAdd(&ssq[o0 + oo], q);
        }
        *(float4*)&yb[(size_t)(o0 + oo) * N_ + t0] =
            make_float4(acc[oo][0], acc[oo][1], acc[oo][2], acc[oo][3]);
    }
}

// ---------------------------------------------------------------------------
// K4: finalize BN stats -> per-channel scale/shift
__global__ void finalize_stats(const float* __restrict__ sums,
                               const float* __restrict__ gamma,
                               const float* __restrict__ beta,
                               float* __restrict__ ss) {
    int o = threadIdx.x;
    if (o >= COUT_) return;
    const float invn = 1.0f / (float)NTOK_;
    float mean = sums[o] * invn;
    float var  = sums[COUT_ + o] * invn - mean * mean;
    float sc   = gamma[o] * rsqrtf(var + BN_EPS);
    ss[o]         = sc;
    ss[COUT_ + o] = beta[o] - mean * sc;
}

// K5: y -> BN affine -> exact GELU -> fp32 out
__global__ __launch_bounds__(256) void bn_gelu_out(const float* __restrict__ y,
                                                   const float* __restrict__ ss,
                                                   float* __restrict__ out) {
    const int total4 = (B_ * COUT_ * N_) / 4;
    int i = blockIdx.x * 256 + threadIdx.x;
    if (i >= total4) return;
    int base = i * 4;
    int o = (base / N_) % COUT_;
    float sc = ss[o], sh = ss[COUT_ + o];
    float4 v = *(const float4*)&y[base];
    float u0 = fmaf(v.x, sc, sh), u1 = fmaf(v.y, sc, sh);
    float u2 = fmaf(v.z, sc, sh), u3 = fmaf(v.w, sc, sh);
    const float k = 0.70710678118654752f;
    float4 g;
    g.x = 0.5f * u0 * (1.0f + erff(u0 * k));
    g.y = 0.5f * u1 * (1.0f + erff(u1 * k));
    g.z = 0.5f * u2 * (1.0f + erff(u2 * k));
    g.w = 0.5f * u3 * (1.0f + erff(u3 * k));
    *(float4*)&out[base] = g;
}

// ---------------------------------------------------------------------------
extern "C" void kernel_launch(void* const* d_in, const int* in_sizes, int n_in,
                              void* d_out, int out_size, void* d_ws, size_t ws_size,
                              hipStream_t stream) {
    const float* x     = (const float*)d_in[0];
    const float* w     = (const float*)d_in[1];
    const float* cb    = (const float*)d_in[2];
    const float* gamma = (const float*)d_in[3];
    const float* beta  = (const float*)d_in[4];

    u16* xt_hi = (u16*)d_ws;                         // BNC bf16
    u16* xt_lo = xt_hi + (size_t)BNC;                // BNC bf16
    u16* xc_hi = xt_lo + (size_t)BNC;                // BNC bf16
    float* attT  = (float*)(xc_hi + (size_t)BNC);    // BNC fp32 (channel-major, unnormalized)
    float* WT    = attT + (size_t)BNC;               // 192*192
    float* y     = WT + COUT_ * COUT_;               // B*COUT*N fp32
    float* sums  = y + (size_t)B_ * COUT_ * N_;      // 2*COUT
    float* ss    = sums + 2 * COUT_;                 // 2*COUT
    float* l_arr = ss + 2 * COUT_;                   // NTOK
    float* norm2 = l_arr + NTOK_;                    // NTOK
    int*   maxb  = (int*)(norm2 + NTOK_);            // 1

    hipMemsetAsync(sums, 0, 2 * COUT_ * sizeof(float), stream);
    hipMemsetAsync(l_arr, 0, NTOK_ * sizeof(float), stream);
    hipMemsetAsync(attT, 0, (size_t)BNC * sizeof(float), stream);
    hipMemsetAsync(maxb, 0, sizeof(int), stream);

    transpose_split<<<dim3(N_ / 32, C_ / 32, B_), 256, 0, stream>>>(x, xt_hi, xt_lo, xc_hi);
    transpose_w<<<dim3(COUT_ / 32, COUT_ / 32), 256, 0, stream>>>(w, WT);
    token_norms<<<dim3(NTOK_ / 256), 256, 0, stream>>>(x, norm2, maxb);
    flash_attn_mfma32<<<dim3((N_ + 127) / 128, B_, NSPLIT), 256, 0, stream>>>(
        xt_hi, xt_lo, xc_hi, norm2, maxb, attT, l_arr);
    conv_bn_stats<<<dim3(B_ * (N_ / 64)), 256, 0, stream>>>(x, attT, l_arr, WT, cb, y, sums);
    finalize_stats<<<1, COUT_, 0, stream>>>(sums, gamma, beta, ss);
    bn_gelu_out<<<dim3((B_ * COUT_ * N_ / 4 + 255) / 256), 256, 0, stream>>>(y, ss, (float*)d_out);
}

// Round 8
// 299.115 us; speedup vs baseline: 3.1804x; 1.3660x over previous
//
#include <hip/hip_runtime.h>
#include <hip/hip_bf16.h>

// Problem constants
#define B_    8
#define C_    96
#define N_    3136      // 56*56
#define COUT_ 192
#define NTOK_ 25088     // B_*N_
#define BN_EPS 1e-5f

#define QROW 104        // K LDS token-row stride in bf16 (96+8), 16B-multiple rows
#define VROW 72         // VT row stride in bf16 (64+8), 16B-multiple
#define CROW 200        // conv cat LDS token-row stride in bf16 (192+8), 16B-multiple
#define BNC  (B_ * N_ * C_)
#define NSPLIT 4

typedef __hip_bfloat16 bf16;
typedef unsigned short u16;
typedef unsigned int u32;
typedef __attribute__((ext_vector_type(8))) short short8;    // 8 bf16 (MFMA A/B frag)
typedef __attribute__((ext_vector_type(16))) float f32x16;   // 32x32 MFMA C/D frag

__device__ __forceinline__ u16 f2bf(float f) {
    union { __hip_bfloat16 h; u16 u; } cv;
    cv.h = __float2bfloat16(f);
    return cv.u;
}
__device__ __forceinline__ float bf2f(u16 v) {
    union { u16 u; __hip_bfloat16 h; } cv;
    cv.u = v;
    return __bfloat162float(cv.h);
}
__device__ __forceinline__ u32 packbf2(float lo, float hi) {
    return ((u32)f2bf(hi) << 16) | (u32)f2bf(lo);
}

// ---------------------------------------------------------------------------
// K1: x [B][C][N] fp32 -> xt_hi/xt_lo [B][N][C] bf16 (token-major, hi/lo split)
//                         xc_hi [B][C][N] bf16 (channel-major, for V^T staging)
__global__ __launch_bounds__(256) void transpose_split(const float* __restrict__ x,
                                                       u16* __restrict__ xt_hi,
                                                       u16* __restrict__ xt_lo,
                                                       u16* __restrict__ xc_hi) {
    __shared__ float tile[32][33];
    const int nb = blockIdx.x * 32;
    const int cb = blockIdx.y * 32;
    const int b  = blockIdx.z;
    const int tx = threadIdx.x & 31;
    const int ty = threadIdx.x >> 5;
#pragma unroll
    for (int r = 0; r < 32; r += 8) {
        size_t idx = ((size_t)b * C_ + cb + ty + r) * N_ + nb + tx;
        float v = x[idx];
        tile[ty + r][tx] = v;
        xc_hi[idx] = f2bf(v);
    }
    __syncthreads();
#pragma unroll
    for (int r = 0; r < 32; r += 8) {
        float v = tile[tx][ty + r];
        u16 h = f2bf(v);
        size_t o = ((size_t)b * N_ + nb + ty + r) * C_ + cb + tx;
        xt_hi[o] = h;
        xt_lo[o] = f2bf(v - bf2f(h));
    }
}

// K1b: conv_w [O][2C] fp32 -> whi/wlo bf16 (same [o][c] layout, hi/lo split)
__global__ __launch_bounds__(256) void cast_w(const float* __restrict__ w,
                                              u16* __restrict__ whi,
                                              u16* __restrict__ wlo) {
    int i = blockIdx.x * 256 + threadIdx.x;
    if (i >= COUT_ * 2 * C_) return;
    float v = w[i];
    u16 h = f2bf(v);
    whi[i] = h;
    wlo[i] = f2bf(v - bf2f(h));
}

// K1c: per-token squared norm + global max (fixed-max softmax bound)
__global__ __launch_bounds__(256) void token_norms(const float* __restrict__ x,
                                                   float* __restrict__ norm2,
                                                   int* __restrict__ maxbits) {
    const int idx = blockIdx.x * 256 + threadIdx.x;   // 98*256 == NTOK_
    const int b = idx / N_;
    const int n = idx - b * N_;
    const float* xb = x + (size_t)b * C_ * N_ + n;
    float s = 0.0f;
#pragma unroll
    for (int c = 0; c < C_; c++) {
        float v = xb[(size_t)c * N_];
        s = fmaf(v, v, s);
    }
    norm2[idx] = s;
    float m = s;
#pragma unroll
    for (int d = 1; d < 64; d <<= 1) m = fmaxf(m, __shfl_xor(m, d));
    __shared__ float wmax[4];
    if ((threadIdx.x & 63) == 0) wmax[threadIdx.x >> 6] = m;
    __syncthreads();
    if (threadIdx.x == 0) {
        float mm = fmaxf(fmaxf(wmax[0], wmax[1]), fmaxf(wmax[2], wmax[3]));
        atomicMax(maxbits, __float_as_int(mm));   // norms >= 0 -> int compare ok
    }
}

// ---------------------------------------------------------------------------
// K2: MFMA flash attention, transposed-S formulation, 4-way split-K.
// (unchanged from R7 — HW-verified)
__global__ __launch_bounds__(256, 3) void flash_attn_mfma32(const u16* __restrict__ xt_hi,
                                                            const u16* __restrict__ xt_lo,
                                                            const u16* __restrict__ xc_hi,
                                                            const float* __restrict__ norm2,
                                                            const int* __restrict__ maxbits,
                                                            float* __restrict__ attT,
                                                            float* __restrict__ l_arr) {
    __shared__ u16 Kh[64 * QROW];
    __shared__ u16 Kl[64 * QROW];
    __shared__ u16 VT[96 * VROW];
    const int b     = blockIdx.y;
    const int i0    = blockIdx.x * 128;
    const int split = blockIdx.z;
    const int kt0   = (49 * split) / NSPLIT;
    const int kt1   = (49 * (split + 1)) / NSPLIT;
    const int tid   = threadIdx.x;
    const int lane  = tid & 63;
    const int w     = tid >> 6;
    const int col   = lane & 31;
    const int g     = lane >> 5;

    const u16* th = xt_hi + (size_t)b * N_ * C_;
    const u16* tl = xt_lo + (size_t)b * N_ * C_;
    const u16* vh = xc_hi + (size_t)b * C_ * N_;

    const int qrow  = i0 + w * 32 + col;
    const int qrowc = qrow < N_ ? qrow : N_ - 1;
    short8 qh[6], ql[6];
#pragma unroll
    for (int kc = 0; kc < 6; kc++) {
        qh[kc] = *(const short8*)&th[(size_t)qrowc * C_ + kc * 16 + g * 8];
        ql[kc] = *(const short8*)&tl[(size_t)qrowc * C_ + kc * 16 + g * 8];
    }
    const float maxn2 = __int_as_float(*maxbits);
    const float m_i   = sqrtf(norm2[(size_t)b * N_ + qrowc] * maxn2);
    float l_acc = 0.0f;
    f32x16 O0 = {0}, O1 = {0}, O2 = {0};

    for (int kt = kt0; kt < kt1; kt++) {
        const int n0 = kt * 64;
        __syncthreads();
        for (int e = tid; e < 1536; e += 256) {
            int r = e / 24, c = (e % 24) * 4;
            *(ushort4*)&Kh[r * QROW + c] = *(const ushort4*)&th[(size_t)(n0 + r) * C_ + c];
            *(ushort4*)&Kl[r * QROW + c] = *(const ushort4*)&tl[(size_t)(n0 + r) * C_ + c];
        }
        for (int e = tid; e < 1536; e += 256) {
            int r = e / 16, j = (e % 16) * 4;
            *(ushort4*)&VT[r * VROW + j] = *(const ushort4*)&vh[(size_t)r * N_ + n0 + j];
        }
        __syncthreads();

        u32 w8[2][8];
#pragma unroll
        for (int jt = 0; jt < 2; jt++) {
            f32x16 S = {0};
#pragma unroll
            for (int kc = 0; kc < 6; kc++) {
                short8 kh = *(const short8*)&Kh[(jt * 32 + col) * QROW + kc * 16 + g * 8];
                short8 kl = *(const short8*)&Kl[(jt * 32 + col) * QROW + kc * 16 + g * 8];
                S = __builtin_amdgcn_mfma_f32_32x32x16_bf16(kh, ql[kc], S, 0, 0, 0);
                S = __builtin_amdgcn_mfma_f32_32x32x16_bf16(kl, qh[kc], S, 0, 0, 0);
                S = __builtin_amdgcn_mfma_f32_32x32x16_bf16(kh, qh[kc], S, 0, 0, 0);
            }
            float p[16];
#pragma unroll
            for (int r = 0; r < 16; r++) {
                p[r] = __expf(S[r] - m_i);
                l_acc += p[r];
            }
#pragma unroll
            for (int q = 0; q < 8; q++) w8[jt][q] = packbf2(p[2 * q], p[2 * q + 1]);
        }

#pragma unroll
        for (int kc = 0; kc < 4; kc++) {
            const int jt = kc >> 1, qb = (kc & 1) * 4;
            u32 a0 = w8[jt][qb + 0], a1 = w8[jt][qb + 1];
            u32 a2 = w8[jt][qb + 2], a3 = w8[jt][qb + 3];
            u32 s0 = __shfl_xor((int)a0, 32), s1 = __shfl_xor((int)a1, 32);
            u32 s2 = __shfl_xor((int)a2, 32), s3 = __shfl_xor((int)a3, 32);
            union { short8 v; u32 u[4]; } Bf;
            Bf.u[0] = g ? s2 : a0;
            Bf.u[1] = g ? s3 : a1;
            Bf.u[2] = g ? a2 : s0;
            Bf.u[3] = g ? a3 : s1;
            short8 v0 = *(const short8*)&VT[(col)      * VROW + kc * 16 + g * 8];
            short8 v1 = *(const short8*)&VT[(32 + col) * VROW + kc * 16 + g * 8];
            short8 v2 = *(const short8*)&VT[(64 + col) * VROW + kc * 16 + g * 8];
            O0 = __builtin_amdgcn_mfma_f32_32x32x16_bf16(v0, Bf.v, O0, 0, 0, 0);
            O1 = __builtin_amdgcn_mfma_f32_32x32x16_bf16(v1, Bf.v, O1, 0, 0, 0);
            O2 = __builtin_amdgcn_mfma_f32_32x32x16_bf16(v2, Bf.v, O2, 0, 0, 0);
        }
    }

    if (qrow < N_) {
        float* ab = attT + (size_t)b * C_ * N_ + qrow;
#pragma unroll
        for (int r = 0; r < 16; r++) {
            int c = (r & 3) + 8 * (r >> 2) + 4 * g;
            atomicAdd(&ab[(size_t)(c)      * N_], O0[r]);
            atomicAdd(&ab[(size_t)(c + 32) * N_], O1[r]);
            atomicAdd(&ab[(size_t)(c + 64) * N_], O2[r]);
        }
        float l_tot = l_acc + __shfl_xor(l_acc, 32);
        if (g == 0) atomicAdd(&l_arr[(size_t)b * N_ + qrow], l_tot);
    }
}

// ---------------------------------------------------------------------------
// K3: MFMA 1x1 conv: y[b][o][n] = W[o][:] . cat[:][n] + bias.
// GEMM M=192(out) N=64(tokens) K=192. A=W rows (bf16 hi/lo, global/L2),
// B=cat tile (LDS, token-major bf16 hi/lo, relu fused at staging).
// 4 waves: wave w -> N-subtile (w&1), M-tiles 3*(w>>1)..+2.
// C/D: col=token, row->o. Split terms: Whi*clo + Wlo*chi + Whi*chi.
__global__ __launch_bounds__(256, 3) void conv_mfma(const float* __restrict__ x,
                                                    const float* __restrict__ attT,
                                                    const float* __restrict__ l_arr,
                                                    const u16* __restrict__ whi,
                                                    const u16* __restrict__ wlo,
                                                    const float* __restrict__ convb,
                                                    float* __restrict__ y) {
    __shared__ u16 ch[64 * CROW];    // 25.6 KB
    __shared__ u16 cl[64 * CROW];    // 25.6 KB
    __shared__ float invl[64];
    const int b   = blockIdx.x / (N_ / 64);
    const int n0  = (blockIdx.x % (N_ / 64)) * 64;
    const int tid = threadIdx.x;

    if (tid < 64) invl[tid] = 1.0f / l_arr[(size_t)b * N_ + n0 + tid];
    __syncthreads();

    const float* xb = x    + (size_t)b * C_ * N_ + n0;
    const float* ab = attT + (size_t)b * C_ * N_ + n0;
    for (int e = tid; e < 64 * C_; e += 256) {
        int c = e >> 6, t = e & 63;
        float xv = xb[(size_t)c * N_ + t];
        float au = ab[(size_t)c * N_ + t];
        float xj = fmaxf(xv - au * invl[t], 0.0f);
        u16 h1 = f2bf(xv);
        ch[t * CROW + c] = h1;
        cl[t * CROW + c] = f2bf(xv - bf2f(h1));
        u16 h2 = f2bf(xj);
        ch[t * CROW + C_ + c] = h2;
        cl[t * CROW + C_ + c] = f2bf(xj - bf2f(h2));
    }
    __syncthreads();

    const int lane = tid & 63;
    const int w    = tid >> 6;
    const int col  = lane & 31;
    const int g    = lane >> 5;
    const int nt   = w & 1;          // 32-token N-subtile
    const int m0   = (w >> 1) * 3;   // first of 3 M-tiles

    f32x16 A[3] = {{0}, {0}, {0}};
#pragma unroll
    for (int ks = 0; ks < 12; ks++) {
        const int k0 = ks * 16;
        short8 bh = *(const short8*)&ch[(nt * 32 + col) * CROW + k0 + g * 8];
        short8 bl = *(const short8*)&cl[(nt * 32 + col) * CROW + k0 + g * 8];
#pragma unroll
        for (int mt = 0; mt < 3; mt++) {
            const size_t wo = (size_t)((m0 + mt) * 32 + col) * (2 * C_) + k0 + g * 8;
            short8 ah = *(const short8*)&whi[wo];
            short8 al = *(const short8*)&wlo[wo];
            A[mt] = __builtin_amdgcn_mfma_f32_32x32x16_bf16(ah, bl, A[mt], 0, 0, 0);
            A[mt] = __builtin_amdgcn_mfma_f32_32x32x16_bf16(al, bh, A[mt], 0, 0, 0);
            A[mt] = __builtin_amdgcn_mfma_f32_32x32x16_bf16(ah, bh, A[mt], 0, 0, 0);
        }
    }

    float* yb = y + (size_t)b * COUT_ * N_ + n0 + nt * 32 + col;
#pragma unroll
    for (int mt = 0; mt < 3; mt++)
#pragma unroll
        for (int r = 0; r < 16; r++) {
            int o = (m0 + mt) * 32 + (r & 3) + 8 * (r >> 2) + 4 * g;
            yb[(size_t)o * N_] = A[mt][r] + convb[o];
        }
}

// ---------------------------------------------------------------------------
// K4: per-channel BN stats from y -> scale/shift (one block per channel)
__global__ __launch_bounds__(256) void bn_stats(const float* __restrict__ y,
                                                const float* __restrict__ gamma,
                                                const float* __restrict__ beta,
                                                float* __restrict__ ss) {
    const int o   = blockIdx.x;
    const int tid = threadIdx.x;
    float s = 0.0f, q = 0.0f;
#pragma unroll
    for (int b = 0; b < B_; b++) {
        const float4* p = (const float4*)(y + (size_t)(b * COUT_ + o) * N_);
        for (int i = tid; i < N_ / 4; i += 256) {
            float4 v = p[i];
            s += v.x + v.y + v.z + v.w;
            q += v.x * v.x + v.y * v.y + v.z * v.z + v.w * v.w;
        }
    }
#pragma unroll
    for (int d = 1; d < 64; d <<= 1) {
        s += __shfl_xor(s, d);
        q += __shfl_xor(q, d);
    }
    __shared__ float wss[4], wqq[4];
    if ((tid & 63) == 0) { wss[tid >> 6] = s; wqq[tid >> 6] = q; }
    __syncthreads();
    if (tid == 0) {
        float st = wss[0] + wss[1] + wss[2] + wss[3];
        float qt = wqq[0] + wqq[1] + wqq[2] + wqq[3];
        const float invn = 1.0f / (float)NTOK_;
        float mean = st * invn;
        float var  = qt * invn - mean * mean;
        float sc   = gamma[o] * rsqrtf(var + BN_EPS);
        ss[o]         = sc;
        ss[COUT_ + o] = beta[o] - mean * sc;
    }
}

// K5: y -> BN affine -> exact GELU -> fp32 out
__global__ __launch_bounds__(256) void bn_gelu_out(const float* __restrict__ y,
                                                   const float* __restrict__ ss,
                                                   float* __restrict__ out) {
    const int total4 = (B_ * COUT_ * N_) / 4;
    int i = blockIdx.x * 256 + threadIdx.x;
    if (i >= total4) return;
    int base = i * 4;
    int o = (base / N_) % COUT_;
    float sc = ss[o], sh = ss[COUT_ + o];
    float4 v = *(const float4*)&y[base];
    float u0 = fmaf(v.x, sc, sh), u1 = fmaf(v.y, sc, sh);
    float u2 = fmaf(v.z, sc, sh), u3 = fmaf(v.w, sc, sh);
    const float k = 0.70710678118654752f;
    float4 g;
    g.x = 0.5f * u0 * (1.0f + erff(u0 * k));
    g.y = 0.5f * u1 * (1.0f + erff(u1 * k));
    g.z = 0.5f * u2 * (1.0f + erff(u2 * k));
    g.w = 0.5f * u3 * (1.0f + erff(u3 * k));
    *(float4*)&out[base] = g;
}

// ---------------------------------------------------------------------------
extern "C" void kernel_launch(void* const* d_in, const int* in_sizes, int n_in,
                              void* d_out, int out_size, void* d_ws, size_t ws_size,
                              hipStream_t stream) {
    const float* x     = (const float*)d_in[0];
    const float* w     = (const float*)d_in[1];
    const float* cb    = (const float*)d_in[2];
    const float* gamma = (const float*)d_in[3];
    const float* beta  = (const float*)d_in[4];

    u16* xt_hi = (u16*)d_ws;                         // BNC bf16
    u16* xt_lo = xt_hi + (size_t)BNC;                // BNC
    u16* xc_hi = xt_lo + (size_t)BNC;                // BNC
    float* attT  = (float*)(xc_hi + (size_t)BNC);    // BNC fp32 (channel-major, unnormalized)
    u16* whi   = (u16*)(attT + (size_t)BNC);         // 192*192 bf16
    u16* wlo   = whi + COUT_ * 2 * C_;               // 192*192 bf16
    float* y     = (float*)(wlo + COUT_ * 2 * C_);   // B*COUT*N fp32
    float* ss    = y + (size_t)B_ * COUT_ * N_;      // 2*COUT
    float* l_arr = ss + 2 * COUT_;                   // NTOK
    float* norm2 = l_arr + NTOK_;                    // NTOK
    int*   maxb  = (int*)(norm2 + NTOK_);            // 1

    hipMemsetAsync(l_arr, 0, NTOK_ * sizeof(float), stream);
    hipMemsetAsync(attT, 0, (size_t)BNC * sizeof(float), stream);
    hipMemsetAsync(maxb, 0, sizeof(int), stream);

    transpose_split<<<dim3(N_ / 32, C_ / 32, B_), 256, 0, stream>>>(x, xt_hi, xt_lo, xc_hi);
    cast_w<<<dim3((COUT_ * 2 * C_ + 255) / 256), 256, 0, stream>>>(w, whi, wlo);
    token_norms<<<dim3(NTOK_ / 256), 256, 0, stream>>>(x, norm2, maxb);
    flash_attn_mfma32<<<dim3((N_ + 127) / 128, B_, NSPLIT), 256, 0, stream>>>(
        xt_hi, xt_lo, xc_hi, norm2, maxb, attT, l_arr);
    conv_mfma<<<dim3(B_ * (N_ / 64)), 256, 0, stream>>>(x, attT, l_arr, whi, wlo, cb, y);
    bn_stats<<<dim3(COUT_), 256, 0, stream>>>(y, gamma, beta, ss);
    bn_gelu_out<<<dim3((B_ * COUT_ * N_ / 4 + 255) / 256), 256, 0, stream>>>(y, ss, (float*)d_out);
}